// Round 1
// baseline (2447.104 us; speedup 1.0000x reference)
//
#include <hip/hip_runtime.h>
#include <math.h>

#define HID 128
#define NRBF 50
#define NLAYERS 6
#define CUTV 5.0f

__device__ __forceinline__ float siluf(float x){ return x / (1.0f + __expf(-x)); }

// ---------------- setup: counting sort of edges by dst ----------------
__global__ void k_zero(int* p, int n){
    int i = blockIdx.x*blockDim.x + threadIdx.x;
    if (i < n) p[i] = 0;
}

__global__ void k_count(const int* ei, int E, int* counts){
    int e = blockIdx.x*blockDim.x + threadIdx.x;
    if (e < E) atomicAdd(&counts[ei[E + e]], 1);
}

__global__ void k_scan(const int* counts, int* offsets, int* cursor, int n){
    // single block of 1024, n <= 8192
    __shared__ int part[1024];
    int tid = threadIdx.x;
    int PER = (n + 1023) >> 10;
    int base = tid * PER;
    int loc[8]; int s = 0;
    #pragma unroll 8
    for (int ii = 0; ii < 8; ii++){
        if (ii < PER){
            int idx = base + ii;
            int c = (idx < n) ? counts[idx] : 0;
            loc[ii] = s; s += c;
        }
    }
    part[tid] = s;
    __syncthreads();
    for (int off = 1; off < 1024; off <<= 1){
        int v = (tid >= off) ? part[tid - off] : 0;
        __syncthreads();
        part[tid] += v;
        __syncthreads();
    }
    int excl = (tid == 0) ? 0 : part[tid - 1];
    #pragma unroll 8
    for (int ii = 0; ii < 8; ii++){
        if (ii < PER){
            int idx = base + ii;
            if (idx < n){ int o = excl + loc[ii]; offsets[idx] = o; cursor[idx] = o; }
        }
    }
    if (tid == 1023) offsets[n] = part[1023];
}

__global__ void k_scatter(const int* ei, int E, int* cursor, int* eperm){
    int e = blockIdx.x*blockDim.x + threadIdx.x;
    if (e < E){
        int d = ei[E + e];
        int pos = atomicAdd(&cursor[d], 1);
        eperm[pos] = e;
    }
}

__global__ void k_edge_vals(const int* ei, const float* edge_vec, const int* eperm, int E,
                            float* ew_p, float* cut_p, float* evn_p, int* src_p, int* ns_p){
    int row = blockIdx.x*blockDim.x + threadIdx.x;
    if (row >= E) return;
    int e = eperm[row];
    int s = ei[e], d = ei[E + e];
    float vx = edge_vec[e*3+0], vy = edge_vec[e*3+1], vz = edge_vec[e*3+2];
    float ew = sqrtf(vx*vx + vy*vy + vz*vz);
    float cut = (ew < CUTV) ? 0.5f*(__cosf(ew * 0.62831853071795864f) + 1.0f) : 0.0f;
    int ns = (s != d) ? 1 : 0;
    float inv = ns ? (1.0f/ew) : 1.0f;
    ew_p[row] = ew; cut_p[row] = cut;
    evn_p[row*3+0] = vx*inv; evn_p[row*3+1] = vy*inv; evn_p[row*3+2] = vz*inv;
    src_p[row] = s; ns_p[row] = ns;
}

// ---------------- neighbor embedding ----------------
__global__ __launch_bounds__(128) void k_ne_agg(
    const int* offsets, const int* src_p, const int* ns_p, const float* ew_p, const float* cut_p,
    const int* z, const float* ne_emb, const float* means, const float* betas,
    const float* dpW, const float* dpb, float* agg){
    int i = blockIdx.x, h = threadIdx.x;
    __shared__ float dpw_s[NRBF*HID];
    __shared__ float mean_s[NRBF], beta_s[NRBF];
    __shared__ float ea_s[NRBF][16];
    __shared__ float u_s[16], cut_s[16];
    __shared__ int   src_s[16];
    for (int idx = h; idx < NRBF*HID; idx += 128) dpw_s[idx] = dpW[idx];
    if (h < NRBF){ mean_s[h] = means[h]; beta_s[h] = betas[h]; }
    float bias = dpb[h];
    float acc = 0.f;
    int r0 = offsets[i], r1 = offsets[i+1];
    for (int t0 = r0; t0 < r1; t0 += 16){
        int nt = min(16, r1 - t0);
        __syncthreads();
        if (h < 16){
            int ok = (h < nt); int row = t0 + h;
            float ew = ok ? ew_p[row] : 0.f;
            u_s[h] = __expf(-ew);
            cut_s[h] = ok ? cut_p[row] : 0.f;
            int sv = -1;
            if (ok && ns_p[row]) sv = src_p[row];
            src_s[h] = sv;
        }
        __syncthreads();
        for (int idx = h; idx < NRBF*16; idx += 128){
            int r = idx >> 4, t = idx & 15;
            float dd = u_s[t] - mean_s[r];
            ea_s[r][t] = cut_s[t] * __expf(-beta_s[r]*dd*dd);
        }
        __syncthreads();
        for (int t = 0; t < nt; t++){
            int s = src_s[t];
            if (s < 0) continue;
            float w = bias;
            #pragma unroll
            for (int r = 0; r < NRBF; r++) w += ea_s[r][t] * dpw_s[r*HID + h];
            w *= cut_s[t];
            acc += w * ne_emb[z[s]*HID + h];
        }
    }
    agg[i*HID + h] = acc;
}

__global__ __launch_bounds__(128) void k_combine(
    const int* z, const float* emb, const float* agg, const float* cbW, const float* cbb,
    float* x, float* vec, int N){
    int n0 = blockIdx.x*8, h = threadIdx.x;
    __shared__ float in_s[8][2*HID];
    #pragma unroll
    for (int m = 0; m < 8; m++){
        int n = n0 + m; if (n >= N) break;
        in_s[m][h]       = emb[z[n]*HID + h];
        in_s[m][HID + h] = agg[n*HID + h];
    }
    __syncthreads();
    float acc[8];
    #pragma unroll
    for (int m = 0; m < 8; m++) acc[m] = 0.f;
    for (int kk = 0; kk < 2*HID; kk++){
        float w = cbW[kk*HID + h];
        #pragma unroll
        for (int m = 0; m < 8; m++) acc[m] += in_s[m][kk]*w;
    }
    float b = cbb[h];
    #pragma unroll
    for (int m = 0; m < 8; m++){
        int n = n0 + m; if (n >= N) break;
        x[n*HID + h] = acc[m] + b;
        vec[(n*3+0)*HID + h] = 0.f;
        vec[(n*3+1)*HID + h] = 0.f;
        vec[(n*3+2)*HID + h] = 0.f;
    }
}

// ---------------- per-layer kernels ----------------
__global__ __launch_bounds__(128) void k_ln(const float* x, const float* w, const float* b,
                                            float* out, int N){
    int n = blockIdx.x, h = threadIdx.x;
    float v = x[n*HID + h];
    float s1 = v, s2 = v*v;
    #pragma unroll
    for (int o = 32; o; o >>= 1){ s1 += __shfl_xor(s1, o, 64); s2 += __shfl_xor(s2, o, 64); }
    __shared__ float r1[2], r2[2];
    int wid = h >> 6;
    if ((h & 63) == 0){ r1[wid] = s1; r2[wid] = s2; }
    __syncthreads();
    float sum = r1[0] + r1[1], sumsq = r2[0] + r2[1];
    float mean = sum * (1.f/HID);
    float var = sumsq * (1.f/HID) - mean*mean;
    float inv = rsqrtf(var + 1e-5f);
    out[n*HID + h] = (v - mean)*inv*w[h] + b[h];
}

// generic 16-row x 128-col tile GEMM, K=128: out(R,C) = in(R,128) @ W(128,C) + bias
template<int C>
__global__ __launch_bounds__(128) void k_gemm(const float* __restrict__ in,
                                              const float* __restrict__ W,
                                              const float* __restrict__ bias,
                                              float* __restrict__ out, int R){
    int j = blockIdx.x*128 + threadIdx.x;
    int r0 = blockIdx.y*16;
    __shared__ float in_s[16][HID];
    for (int idx = threadIdx.x; idx < 16*HID; idx += 128){
        int r = idx >> 7, kk = idx & 127;
        in_s[r][kk] = (r0 + r < R) ? in[(r0 + r)*HID + kk] : 0.f;
    }
    __syncthreads();
    float acc[16];
    #pragma unroll
    for (int t = 0; t < 16; t++) acc[t] = 0.f;
    for (int kk = 0; kk < HID; kk++){
        float w = W[kk*C + j];
        #pragma unroll
        for (int t = 0; t < 16; t++) acc[t] += in_s[t][kk]*w;
    }
    float b = bias ? bias[j] : 0.f;
    int nr = min(16, R - r0);
    for (int t = 0; t < nr; t++) out[(r0 + t)*C + j] = acc[t] + b;
}

__global__ __launch_bounds__(128) void k_vecdot(const float* vecout, float* vec_dot, int N){
    int n = blockIdx.x, h = threadIdx.x;
    float s = 0.f;
    #pragma unroll
    for (int c = 0; c < 3; c++)
        s += vecout[(n*3+c)*384 + h] * vecout[(n*3+c)*384 + HID + h];
    vec_dot[n*HID + h] = s;
}

// fused: dk/dv on-the-fly + attention + per-dst aggregation
__global__ __launch_bounds__(128) void k_edge_agg(
    const int* offsets, const int* src_p, const float* ew_p, const float* cut_p, const float* evn_p,
    const float* means, const float* betas,
    const float* __restrict__ q, const float* __restrict__ kbuf,
    const float* __restrict__ vbuf, const float* __restrict__ vec,
    const float* __restrict__ dkW, const float* __restrict__ dkb,
    const float* __restrict__ dvW, const float* __restrict__ dvb,
    float* xa, float* va){
    int i = blockIdx.x, h = threadIdx.x;
    int head = h >> 4;
    int c0 = head*48 + (h & 15);   // v/dv column for xm; +16 -> w1; +32 -> w2
    __shared__ float q_s[HID];
    __shared__ float mean_s[NRBF], beta_s[NRBF];
    __shared__ float ea_s[NRBF][16];
    __shared__ float u_s[16], cut_s[16];
    __shared__ int src_s[16];
    __shared__ float evn_s[16][3];
    q_s[h] = q[i*HID + h];
    if (h < NRBF){ mean_s[h] = means[h]; beta_s[h] = betas[h]; }
    float dkbh = dkb[h], dvb0 = dvb[c0], dvb1 = dvb[c0+16], dvb2 = dvb[c0+32];
    float axa = 0.f, av0 = 0.f, av1 = 0.f, av2 = 0.f;
    int r0 = offsets[i], r1 = offsets[i+1];
    for (int t0 = r0; t0 < r1; t0 += 16){
        int nt = min(16, r1 - t0);
        __syncthreads();
        if (h < 16){
            int ok = (h < nt); int row = t0 + h;
            float ew = ok ? ew_p[row] : 0.f;
            u_s[h] = __expf(-ew);
            cut_s[h] = ok ? cut_p[row] : 0.f;
            src_s[h] = ok ? src_p[row] : 0;
            evn_s[h][0] = ok ? evn_p[row*3+0] : 0.f;
            evn_s[h][1] = ok ? evn_p[row*3+1] : 0.f;
            evn_s[h][2] = ok ? evn_p[row*3+2] : 0.f;
        }
        __syncthreads();
        for (int idx = h; idx < NRBF*16; idx += 128){
            int r = idx >> 4, t = idx & 15;
            float dd = u_s[t] - mean_s[r];
            ea_s[r][t] = cut_s[t] * __expf(-beta_s[r]*dd*dd);
        }
        __syncthreads();
        float a0[16], a1[16], a2[16], a3[16];
        #pragma unroll
        for (int t = 0; t < 16; t++){ a0[t]=dkbh; a1[t]=dvb0; a2[t]=dvb1; a3[t]=dvb2; }
        for (int r = 0; r < NRBF; r++){
            float w0 = dkW[r*HID + h];
            float w1 = dvW[r*384 + c0];
            float w2 = dvW[r*384 + c0 + 16];
            float w3 = dvW[r*384 + c0 + 32];
            #pragma unroll
            for (int t = 0; t < 16; t++){
                float e = ea_s[r][t];
                a0[t] += e*w0; a1[t] += e*w1; a2[t] += e*w2; a3[t] += e*w3;
            }
        }
        #pragma unroll
        for (int t = 0; t < 16; t++){
            if (t >= nt) break;
            int s = src_s[t];
            float dk = siluf(a0[t]);
            float p = q_s[h] * kbuf[s*HID + h] * dk;
            p += __shfl_xor(p, 1, 64);
            p += __shfl_xor(p, 2, 64);
            p += __shfl_xor(p, 4, 64);
            p += __shfl_xor(p, 8, 64);
            float attn = siluf(p) * cut_s[t];
            float dv0 = siluf(a1[t]), dv1 = siluf(a2[t]), dv2 = siluf(a3[t]);
            const float* vrow = vbuf + s*384;
            axa += vrow[c0]*dv0*attn;
            float w1v = vrow[c0+16]*dv1;
            float w2v = vrow[c0+32]*dv2;
            const float* vc = vec + s*3*HID;
            av0 += vc[h]*w1v         + w2v*evn_s[t][0];
            av1 += vc[HID + h]*w1v   + w2v*evn_s[t][1];
            av2 += vc[2*HID + h]*w1v + w2v*evn_s[t][2];
        }
    }
    xa[i*HID + h] = axa;
    va[(i*3+0)*HID + h] = av0;
    va[(i*3+1)*HID + h] = av1;
    va[(i*3+2)*HID + h] = av2;
}

__global__ __launch_bounds__(128) void k_update(float* x, float* vec, const float* vec_dot,
    const float* o, const float* vecout, const float* va, int N){
    int n = blockIdx.x, h = threadIdx.x;
    const float* on = o + n*384;
    x[n*HID + h] += vec_dot[n*HID + h]*on[HID + h] + on[2*HID + h];
    float o1 = on[h];
    #pragma unroll
    for (int c = 0; c < 3; c++){
        int idx = (n*3+c)*HID + h;
        vec[idx] += vecout[(n*3+c)*384 + 2*HID + h]*o1 + va[idx];
    }
}

__global__ __launch_bounds__(128) void k_final_ln(const float* x, const float* w, const float* b,
                                                  float* out, int N){
    int n = blockIdx.x, h = threadIdx.x;
    float v = x[n*HID + h];
    float s1 = v, s2 = v*v;
    #pragma unroll
    for (int o = 32; o; o >>= 1){ s1 += __shfl_xor(s1, o, 64); s2 += __shfl_xor(s2, o, 64); }
    __shared__ float r1[2], r2[2];
    int wid = h >> 6;
    if ((h & 63) == 0){ r1[wid] = s1; r2[wid] = s2; }
    __syncthreads();
    float sum = r1[0] + r1[1], sumsq = r2[0] + r2[1];
    float mean = sum * (1.f/HID);
    float var = sumsq * (1.f/HID) - mean*mean;
    float inv = rsqrtf(var + 1e-5f);
    out[n*HID + h] = (v - mean)*inv*w[h] + b[h];
}

__global__ void k_copy(const float* src, float* dst, int n){
    int i = blockIdx.x*blockDim.x + threadIdx.x;
    if (i < n) dst[i] = src[i];
}

// ---------------- host ----------------
extern "C" void kernel_launch(void* const* d_in, const int* in_sizes, int n_in,
                              void* d_out, int out_size, void* d_ws, size_t ws_size,
                              hipStream_t stream){
    const int*   z        = (const int*)  d_in[0];
    const int*   ei       = (const int*)  d_in[1];
    const float* edge_vec = (const float*)d_in[2];
    const float* emb      = (const float*)d_in[3];
    const float* means    = (const float*)d_in[4];
    const float* betas    = (const float*)d_in[5];
    const float* ne_emb   = (const float*)d_in[6];
    const float* dpW      = (const float*)d_in[7];
    const float* dpb      = (const float*)d_in[8];
    const float* cbW      = (const float*)d_in[9];
    const float* cbb      = (const float*)d_in[10];
    const float* lnw      = (const float*)d_in[11];
    const float* lnb      = (const float*)d_in[12];
    const float* qW       = (const float*)d_in[13];
    const float* qb       = (const float*)d_in[14];
    const float* kW       = (const float*)d_in[15];
    const float* kb       = (const float*)d_in[16];
    const float* vW       = (const float*)d_in[17];
    const float* vb       = (const float*)d_in[18];
    const float* oW       = (const float*)d_in[19];
    const float* obias    = (const float*)d_in[20];
    const float* vecW     = (const float*)d_in[21];
    const float* dkW      = (const float*)d_in[22];
    const float* dkb      = (const float*)d_in[23];
    const float* dvW      = (const float*)d_in[24];
    const float* dvb      = (const float*)d_in[25];
    const float* onw      = (const float*)d_in[26];
    const float* onb      = (const float*)d_in[27];

    int N = in_sizes[0];
    int E = in_sizes[1] / 2;

    char* p = (char*)d_ws;
    auto alloc = [&](size_t bytes){ void* r = (void*)p; p += (bytes + 255) & ~(size_t)255; return r; };
    int*   counts  = (int*)  alloc((size_t)N*4);
    int*   offsets = (int*)  alloc((size_t)(N+1)*4);
    int*   cursor  = (int*)  alloc((size_t)N*4);
    int*   eperm   = (int*)  alloc((size_t)E*4);
    int*   src_p   = (int*)  alloc((size_t)E*4);
    int*   ns_p    = (int*)  alloc((size_t)E*4);
    float* ew_p    = (float*)alloc((size_t)E*4);
    float* cut_p   = (float*)alloc((size_t)E*4);
    float* evn_p   = (float*)alloc((size_t)E*12);
    float* agg     = (float*)alloc((size_t)N*HID*4);
    float* xb      = (float*)alloc((size_t)N*HID*4);
    float* hb      = (float*)alloc((size_t)N*HID*4);
    float* qb_     = (float*)alloc((size_t)N*HID*4);
    float* kb_     = (float*)alloc((size_t)N*HID*4);
    float* vb_     = (float*)alloc((size_t)N*384*4);
    float* vecb    = (float*)alloc((size_t)N*384*4);
    float* vecout  = (float*)alloc((size_t)N*3*384*4);
    float* vdot    = (float*)alloc((size_t)N*HID*4);
    float* xab     = (float*)alloc((size_t)N*HID*4);
    float* vab     = (float*)alloc((size_t)N*384*4);
    float* ob_     = (float*)alloc((size_t)N*384*4);

    k_zero<<<(N+255)/256, 256, 0, stream>>>(counts, N);
    k_count<<<(E+255)/256, 256, 0, stream>>>(ei, E, counts);
    k_scan<<<1, 1024, 0, stream>>>(counts, offsets, cursor, N);
    k_scatter<<<(E+255)/256, 256, 0, stream>>>(ei, E, cursor, eperm);
    k_edge_vals<<<(E+255)/256, 256, 0, stream>>>(ei, edge_vec, eperm, E, ew_p, cut_p, evn_p, src_p, ns_p);

    k_ne_agg<<<N, 128, 0, stream>>>(offsets, src_p, ns_p, ew_p, cut_p, z, ne_emb, means, betas,
                                     dpW, dpb, agg);
    k_combine<<<(N+7)/8, 128, 0, stream>>>(z, emb, agg, cbW, cbb, xb, vecb, N);

    for (int l = 0; l < NLAYERS; l++){
        k_ln<<<N, 128, 0, stream>>>(xb, lnw + l*HID, lnb + l*HID, hb, N);
        k_gemm<128><<<dim3(1,(N+15)/16), 128, 0, stream>>>(hb, qW + (size_t)l*HID*HID, qb + l*HID, qb_, N);
        k_gemm<128><<<dim3(1,(N+15)/16), 128, 0, stream>>>(hb, kW + (size_t)l*HID*HID, kb + l*HID, kb_, N);
        k_gemm<384><<<dim3(3,(N+15)/16), 128, 0, stream>>>(hb, vW + (size_t)l*HID*384, vb + l*384, vb_, N);
        k_gemm<384><<<dim3(3,(3*N+15)/16), 128, 0, stream>>>(vecb, vecW + (size_t)l*HID*384, nullptr, vecout, 3*N);
        k_vecdot<<<N, 128, 0, stream>>>(vecout, vdot, N);
        k_edge_agg<<<N, 128, 0, stream>>>(offsets, src_p, ew_p, cut_p, evn_p, means, betas,
                                          qb_, kb_, vb_, vecb,
                                          dkW + (size_t)l*NRBF*HID, dkb + l*HID,
                                          dvW + (size_t)l*NRBF*384, dvb + l*384,
                                          xab, vab);
        k_gemm<384><<<dim3(3,(N+15)/16), 128, 0, stream>>>(xab, oW + (size_t)l*HID*384, obias + l*384, ob_, N);
        k_update<<<N, 128, 0, stream>>>(xb, vecb, vdot, ob_, vecout, vab, N);
    }

    k_final_ln<<<N, 128, 0, stream>>>(xb, onw, onb, (float*)d_out, N);
    k_copy<<<(N*384+255)/256, 256, 0, stream>>>(vecb, (float*)d_out + (size_t)N*HID, N*384);
}

// Round 2
// 1379.402 us; speedup vs baseline: 1.7740x; 1.7740x over previous
//
#include <hip/hip_runtime.h>
#include <math.h>

#define HID 128
#define NRBF 50
#define NLAYERS 6
#define CUTV 5.0f
#define KNOTS 2048           // intervals; rows allocated = KNOTS+2
#define TSCALE 409.6f        // KNOTS / CUTV
#define TINV   0.00244140625f // CUTV / KNOTS

__device__ __forceinline__ float siluf(float x){ return x / (1.0f + __expf(-x)); }
__device__ __forceinline__ float lerpf(float a, float b, float f){ return fmaf(f, b - a, a); }

// ---------------- setup: counting sort of edges by dst ----------------
__global__ void k_zero(int* p, int n){
    int i = blockIdx.x*blockDim.x + threadIdx.x;
    if (i < n) p[i] = 0;
}

__global__ void k_count(const int* ei, int E, int* counts){
    int e = blockIdx.x*blockDim.x + threadIdx.x;
    if (e < E) atomicAdd(&counts[ei[E + e]], 1);
}

__global__ void k_scan(const int* counts, int* offsets, int* cursor, int n){
    __shared__ int part[1024];
    int tid = threadIdx.x;
    int PER = (n + 1023) >> 10;
    int base = tid * PER;
    int loc[8]; int s = 0;
    #pragma unroll 8
    for (int ii = 0; ii < 8; ii++){
        if (ii < PER){
            int idx = base + ii;
            int c = (idx < n) ? counts[idx] : 0;
            loc[ii] = s; s += c;
        }
    }
    part[tid] = s;
    __syncthreads();
    for (int off = 1; off < 1024; off <<= 1){
        int v = (tid >= off) ? part[tid - off] : 0;
        __syncthreads();
        part[tid] += v;
        __syncthreads();
    }
    int excl = (tid == 0) ? 0 : part[tid - 1];
    #pragma unroll 8
    for (int ii = 0; ii < 8; ii++){
        if (ii < PER){
            int idx = base + ii;
            if (idx < n){ int o = excl + loc[ii]; offsets[idx] = o; cursor[idx] = o; }
        }
    }
    if (tid == 1023) offsets[n] = part[1023];
}

__global__ void k_scatter(const int* ei, int E, int* cursor, int* eperm){
    int e = blockIdx.x*blockDim.x + threadIdx.x;
    if (e < E){
        int d = ei[E + e];
        int pos = atomicAdd(&cursor[d], 1);
        eperm[pos] = e;
    }
}

// per-edge precompute: packed scalars + normalized vec
__global__ void k_edge_vals(const int* ei, const float* edge_vec, const int* eperm, int E,
                            int4* edata, float4* evn4){
    int row = blockIdx.x*blockDim.x + threadIdx.x;
    if (row >= E) return;
    int e = eperm[row];
    int s = ei[e], d = ei[E + e];
    float vx = edge_vec[e*3+0], vy = edge_vec[e*3+1], vz = edge_vec[e*3+2];
    float ew = sqrtf(vx*vx + vy*vy + vz*vz);
    float cut = (ew < CUTV) ? 0.5f*(__cosf(ew * 0.62831853071795864f) + 1.0f) : 0.0f;
    int ns = (s != d) ? 1 : 0;
    float inv = ns ? (1.0f/ew) : 1.0f;
    float un = fminf(ew * TSCALE, (float)KNOTS);
    int j = (int)un;
    float f = un - (float)j;
    int4 ed; ed.x = s; ed.y = j; ed.z = __float_as_int(f); ed.w = __float_as_int(cut);
    edata[row] = ed;
    float4 ev; ev.x = vx*inv; ev.y = vy*inv; ev.z = vz*inv; ev.w = ns ? 1.0f : 0.0f;
    evn4[row] = ev;
}

// ---------------- tables ----------------
// layer table: T[knot][0:128] = silu(ea@dkW+dkb); T[knot][128:512] = silu(ea@dvW+dvb)
__global__ __launch_bounds__(512) void k_build_table(
    const float* means, const float* betas,
    const float* dkW, const float* dkb, const float* dvW, const float* dvb,
    float* T){
    int knot = blockIdx.x, c = threadIdx.x;
    __shared__ float ea[NRBF];
    float d = knot * TINV;
    if (c < NRBF){
        float cut = (d < CUTV) ? 0.5f*(__cosf(d * 0.62831853071795864f) + 1.0f) : 0.0f;
        float u = __expf(-d);
        float dd = u - means[c];
        ea[c] = cut * __expf(-betas[c]*dd*dd);
    }
    __syncthreads();
    float acc;
    if (c < HID){
        acc = dkb[c];
        #pragma unroll
        for (int r = 0; r < NRBF; r++) acc += ea[r]*dkW[r*HID + c];
    } else {
        int cc = c - HID;
        acc = dvb[cc];
        #pragma unroll
        for (int r = 0; r < NRBF; r++) acc += ea[r]*dvW[r*384 + cc];
    }
    T[(size_t)knot*512 + c] = siluf(acc);
}

// NE table: Tne[knot][c] = (ea@dpW+dpb)[c] * cut
__global__ __launch_bounds__(128) void k_build_ne(
    const float* means, const float* betas,
    const float* dpW, const float* dpb, float* Tne){
    int knot = blockIdx.x, c = threadIdx.x;
    __shared__ float ea[NRBF];
    float d = knot * TINV;
    float cut = (d < CUTV) ? 0.5f*(__cosf(d * 0.62831853071795864f) + 1.0f) : 0.0f;
    if (c < NRBF){
        float u = __expf(-d);
        float dd = u - means[c];
        ea[c] = cut * __expf(-betas[c]*dd*dd);
    }
    __syncthreads();
    float acc = dpb[c];
    #pragma unroll
    for (int r = 0; r < NRBF; r++) acc += ea[r]*dpW[r*HID + c];
    Tne[(size_t)knot*HID + c] = acc * cut;
}

// ---------------- neighbor embedding ----------------
__global__ __launch_bounds__(128) void k_ne_agg(
    const int* offsets, const int4* edata, const float4* evn4, const float* Tne,
    const int* z, const float* ne_emb, float* agg){
    int i = blockIdx.x, h = threadIdx.x;
    float acc = 0.f;
    int r0 = offsets[i], r1 = offsets[i+1];
    #pragma unroll 2
    for (int row = r0; row < r1; row++){
        int4 ed = edata[row];
        int s = ed.x, j = ed.y;
        float f = __int_as_float(ed.z);
        float mask = evn4[row].w;
        float w = lerpf(Tne[(size_t)j*HID + h], Tne[(size_t)(j+1)*HID + h], f) * mask;
        acc += w * ne_emb[(size_t)z[s]*HID + h];
    }
    agg[(size_t)i*HID + h] = acc;
}

__global__ __launch_bounds__(128) void k_combine(
    const int* z, const float* emb, const float* agg, const float* cbW, const float* cbb,
    float* x, float* vec, int N){
    int n0 = blockIdx.x*8, h = threadIdx.x;
    __shared__ float in_s[8][2*HID];
    #pragma unroll
    for (int m = 0; m < 8; m++){
        int n = n0 + m; if (n >= N) break;
        in_s[m][h]       = emb[(size_t)z[n]*HID + h];
        in_s[m][HID + h] = agg[(size_t)n*HID + h];
    }
    __syncthreads();
    float acc[8];
    #pragma unroll
    for (int m = 0; m < 8; m++) acc[m] = 0.f;
    for (int kk = 0; kk < 2*HID; kk++){
        float w = cbW[kk*HID + h];
        #pragma unroll
        for (int m = 0; m < 8; m++) acc[m] += in_s[m][kk]*w;
    }
    float b = cbb[h];
    #pragma unroll
    for (int m = 0; m < 8; m++){
        int n = n0 + m; if (n >= N) break;
        x[(size_t)n*HID + h] = acc[m] + b;
        vec[(size_t)(n*3+0)*HID + h] = 0.f;
        vec[(size_t)(n*3+1)*HID + h] = 0.f;
        vec[(size_t)(n*3+2)*HID + h] = 0.f;
    }
}

// ---------------- per-layer kernels ----------------
__global__ __launch_bounds__(128) void k_ln(const float* x, const float* w, const float* b,
                                            float* out, int N){
    int n = blockIdx.x, h = threadIdx.x;
    float v = x[(size_t)n*HID + h];
    float s1 = v, s2 = v*v;
    #pragma unroll
    for (int o = 32; o; o >>= 1){ s1 += __shfl_xor(s1, o, 64); s2 += __shfl_xor(s2, o, 64); }
    __shared__ float r1[2], r2[2];
    int wid = h >> 6;
    if ((h & 63) == 0){ r1[wid] = s1; r2[wid] = s2; }
    __syncthreads();
    float sum = r1[0] + r1[1], sumsq = r2[0] + r2[1];
    float mean = sum * (1.f/HID);
    float var = sumsq * (1.f/HID) - mean*mean;
    float inv = rsqrtf(var + 1e-5f);
    out[(size_t)n*HID + h] = (v - mean)*inv*w[h] + b[h];
}

// fused q/k/v GEMM: grid.x in [0,5): 0->q, 1->k, 2..4->v col-blocks
__global__ __launch_bounds__(128) void k_qkv(const float* __restrict__ in,
    const float* __restrict__ qW, const float* __restrict__ qb,
    const float* __restrict__ kW, const float* __restrict__ kb,
    const float* __restrict__ vW, const float* __restrict__ vb,
    float* __restrict__ qo, float* __restrict__ ko, float* __restrict__ vo, int R){
    int bx = blockIdx.x;
    int r0 = blockIdx.y*16;
    __shared__ float in_s[16][HID];
    for (int idx = threadIdx.x; idx < 16*HID; idx += 128){
        int r = idx >> 7, kk = idx & 127;
        in_s[r][kk] = (r0 + r < R) ? in[(size_t)(r0 + r)*HID + kk] : 0.f;
    }
    __syncthreads();
    const float* W; const float* bias; float* out; int stride, col;
    if (bx == 0){ W = qW; bias = qb; out = qo; stride = 128; col = threadIdx.x; }
    else if (bx == 1){ W = kW; bias = kb; out = ko; stride = 128; col = threadIdx.x; }
    else { W = vW; bias = vb; out = vo; stride = 384; col = (bx-2)*128 + threadIdx.x; }
    float acc[16];
    #pragma unroll
    for (int t = 0; t < 16; t++) acc[t] = 0.f;
    for (int kk = 0; kk < HID; kk++){
        float w = W[(size_t)kk*stride + col];
        #pragma unroll
        for (int t = 0; t < 16; t++) acc[t] += in_s[t][kk]*w;
    }
    float b = bias[col];
    int nr = min(16, R - r0);
    for (int t = 0; t < nr; t++) out[(size_t)(r0 + t)*stride + col] = acc[t] + b;
}

// generic 16-row x 128-col tile GEMM, K=128
template<int C>
__global__ __launch_bounds__(128) void k_gemm(const float* __restrict__ in,
                                              const float* __restrict__ W,
                                              const float* __restrict__ bias,
                                              float* __restrict__ out, int R){
    int j = blockIdx.x*128 + threadIdx.x;
    int r0 = blockIdx.y*16;
    __shared__ float in_s[16][HID];
    for (int idx = threadIdx.x; idx < 16*HID; idx += 128){
        int r = idx >> 7, kk = idx & 127;
        in_s[r][kk] = (r0 + r < R) ? in[(size_t)(r0 + r)*HID + kk] : 0.f;
    }
    __syncthreads();
    float acc[16];
    #pragma unroll
    for (int t = 0; t < 16; t++) acc[t] = 0.f;
    for (int kk = 0; kk < HID; kk++){
        float w = W[(size_t)kk*C + j];
        #pragma unroll
        for (int t = 0; t < 16; t++) acc[t] += in_s[t][kk]*w;
    }
    float b = bias ? bias[j] : 0.f;
    int nr = min(16, R - r0);
    for (int t = 0; t < nr; t++) out[(size_t)(r0 + t)*C + j] = acc[t] + b;
}

// fused: table-lookup dk/dv + attention + per-dst aggregation
__global__ __launch_bounds__(128) void k_edge_agg(
    const int* __restrict__ offsets, const int4* __restrict__ edata,
    const float4* __restrict__ evn4, const float* __restrict__ T,
    const float* __restrict__ q, const float* __restrict__ kbuf,
    const float* __restrict__ vbuf, const float* __restrict__ vec,
    float* __restrict__ xa, float* __restrict__ va){
    int i = blockIdx.x, h = threadIdx.x;
    int head = h >> 4;
    int c0 = head*48 + (h & 15);   // v/dv column for xm; +16 -> w1; +32 -> w2
    float qv = q[(size_t)i*HID + h];
    float axa = 0.f, av0 = 0.f, av1 = 0.f, av2 = 0.f;
    int r0 = offsets[i], r1 = offsets[i+1];
    #pragma unroll 2
    for (int row = r0; row < r1; row++){
        int4 ed = edata[row];
        int s = ed.x, j = ed.y;
        float f   = __int_as_float(ed.z);
        float cut = __int_as_float(ed.w);
        const float* t0 = T + (size_t)j*512;
        const float* t1 = t0 + 512;
        float dk = lerpf(t0[h], t1[h], f);
        float p = qv * kbuf[(size_t)s*HID + h] * dk;
        p += __shfl_xor(p, 1, 64);
        p += __shfl_xor(p, 2, 64);
        p += __shfl_xor(p, 4, 64);
        p += __shfl_xor(p, 8, 64);
        float attn = siluf(p) * cut;
        float dv0 = lerpf(t0[128 + c0],      t1[128 + c0],      f);
        float dv1 = lerpf(t0[128 + c0 + 16], t1[128 + c0 + 16], f);
        float dv2 = lerpf(t0[128 + c0 + 32], t1[128 + c0 + 32], f);
        float4 ev = evn4[row];
        const float* vrow = vbuf + (size_t)s*384;
        axa += vrow[c0]*dv0*attn;
        float w1v = vrow[c0+16]*dv1;
        float w2v = vrow[c0+32]*dv2;
        const float* vc = vec + (size_t)s*3*HID;
        av0 += vc[h]*w1v         + w2v*ev.x;
        av1 += vc[HID + h]*w1v   + w2v*ev.y;
        av2 += vc[2*HID + h]*w1v + w2v*ev.z;
    }
    xa[(size_t)i*HID + h] = axa;
    va[(size_t)(i*3+0)*HID + h] = av0;
    va[(size_t)(i*3+1)*HID + h] = av1;
    va[(size_t)(i*3+2)*HID + h] = av2;
}

// fused vecdot + residual update
__global__ __launch_bounds__(128) void k_update(float* x, float* vec,
    const float* o, const float* vecout, const float* va, int N){
    int n = blockIdx.x, h = threadIdx.x;
    const float* vo = vecout + (size_t)n*3*384;
    float vdot = vo[h]*vo[128+h] + vo[384+h]*vo[384+128+h] + vo[768+h]*vo[768+128+h];
    const float* on = o + (size_t)n*384;
    x[(size_t)n*HID + h] += vdot*on[HID + h] + on[2*HID + h];
    float o1 = on[h];
    #pragma unroll
    for (int c = 0; c < 3; c++){
        size_t idx = (size_t)(n*3+c)*HID + h;
        vec[idx] += vo[c*384 + 2*HID + h]*o1 + va[idx];
    }
}

__global__ __launch_bounds__(128) void k_final_ln(const float* x, const float* w, const float* b,
                                                  float* out, int N){
    int n = blockIdx.x, h = threadIdx.x;
    float v = x[(size_t)n*HID + h];
    float s1 = v, s2 = v*v;
    #pragma unroll
    for (int o = 32; o; o >>= 1){ s1 += __shfl_xor(s1, o, 64); s2 += __shfl_xor(s2, o, 64); }
    __shared__ float r1[2], r2[2];
    int wid = h >> 6;
    if ((h & 63) == 0){ r1[wid] = s1; r2[wid] = s2; }
    __syncthreads();
    float sum = r1[0] + r1[1], sumsq = r2[0] + r2[1];
    float mean = sum * (1.f/HID);
    float var = sumsq * (1.f/HID) - mean*mean;
    float inv = rsqrtf(var + 1e-5f);
    out[(size_t)n*HID + h] = (v - mean)*inv*w[h] + b[h];
}

__global__ void k_copy(const float* src, float* dst, int n){
    int i = blockIdx.x*blockDim.x + threadIdx.x;
    if (i < n) dst[i] = src[i];
}

// ---------------- host ----------------
extern "C" void kernel_launch(void* const* d_in, const int* in_sizes, int n_in,
                              void* d_out, int out_size, void* d_ws, size_t ws_size,
                              hipStream_t stream){
    const int*   z        = (const int*)  d_in[0];
    const int*   ei       = (const int*)  d_in[1];
    const float* edge_vec = (const float*)d_in[2];
    const float* emb      = (const float*)d_in[3];
    const float* means    = (const float*)d_in[4];
    const float* betas    = (const float*)d_in[5];
    const float* ne_emb   = (const float*)d_in[6];
    const float* dpW      = (const float*)d_in[7];
    const float* dpb      = (const float*)d_in[8];
    const float* cbW      = (const float*)d_in[9];
    const float* cbb      = (const float*)d_in[10];
    const float* lnw      = (const float*)d_in[11];
    const float* lnb      = (const float*)d_in[12];
    const float* qW       = (const float*)d_in[13];
    const float* qb       = (const float*)d_in[14];
    const float* kW       = (const float*)d_in[15];
    const float* kb       = (const float*)d_in[16];
    const float* vW       = (const float*)d_in[17];
    const float* vb       = (const float*)d_in[18];
    const float* oW       = (const float*)d_in[19];
    const float* obias    = (const float*)d_in[20];
    const float* vecW     = (const float*)d_in[21];
    const float* dkW      = (const float*)d_in[22];
    const float* dkb      = (const float*)d_in[23];
    const float* dvW      = (const float*)d_in[24];
    const float* dvb      = (const float*)d_in[25];
    const float* onw      = (const float*)d_in[26];
    const float* onb      = (const float*)d_in[27];

    int N = in_sizes[0];
    int E = in_sizes[1] / 2;
    const int TROWS = KNOTS + 2;

    char* p = (char*)d_ws;
    auto alloc = [&](size_t bytes){ void* r = (void*)p; p += (bytes + 255) & ~(size_t)255; return r; };
    int*    counts  = (int*)   alloc((size_t)N*4);
    int*    offsets = (int*)   alloc((size_t)(N+1)*4);
    int*    cursor  = (int*)   alloc((size_t)N*4);
    int*    eperm   = (int*)   alloc((size_t)E*4);
    int4*   edata   = (int4*)  alloc((size_t)E*16);
    float4* evn4    = (float4*)alloc((size_t)E*16);
    float*  T       = (float*) alloc((size_t)TROWS*512*4);
    float*  Tne     = (float*) alloc((size_t)TROWS*HID*4);
    float*  agg     = (float*) alloc((size_t)N*HID*4);
    float*  xb      = (float*) alloc((size_t)N*HID*4);
    float*  hb      = (float*) alloc((size_t)N*HID*4);
    float*  qb_     = (float*) alloc((size_t)N*HID*4);
    float*  kb_     = (float*) alloc((size_t)N*HID*4);
    float*  vb_     = (float*) alloc((size_t)N*384*4);
    float*  vecb    = (float*) alloc((size_t)N*384*4);
    float*  vecout  = (float*) alloc((size_t)N*3*384*4);
    float*  xab     = (float*) alloc((size_t)N*HID*4);
    float*  vab     = (float*) alloc((size_t)N*384*4);
    float*  ob_     = (float*) alloc((size_t)N*384*4);

    k_zero<<<(N+255)/256, 256, 0, stream>>>(counts, N);
    k_count<<<(E+255)/256, 256, 0, stream>>>(ei, E, counts);
    k_scan<<<1, 1024, 0, stream>>>(counts, offsets, cursor, N);
    k_scatter<<<(E+255)/256, 256, 0, stream>>>(ei, E, cursor, eperm);
    k_edge_vals<<<(E+255)/256, 256, 0, stream>>>(ei, edge_vec, eperm, E, edata, evn4);

    k_build_ne<<<TROWS, 128, 0, stream>>>(means, betas, dpW, dpb, Tne);
    k_ne_agg<<<N, 128, 0, stream>>>(offsets, edata, evn4, Tne, z, ne_emb, agg);
    k_combine<<<(N+7)/8, 128, 0, stream>>>(z, emb, agg, cbW, cbb, xb, vecb, N);

    for (int l = 0; l < NLAYERS; l++){
        k_build_table<<<TROWS, 512, 0, stream>>>(means, betas,
            dkW + (size_t)l*NRBF*HID, dkb + (size_t)l*HID,
            dvW + (size_t)l*NRBF*384, dvb + (size_t)l*384, T);
        k_ln<<<N, 128, 0, stream>>>(xb, lnw + (size_t)l*HID, lnb + (size_t)l*HID, hb, N);
        k_qkv<<<dim3(5,(N+15)/16), 128, 0, stream>>>(hb,
            qW + (size_t)l*HID*HID, qb + (size_t)l*HID,
            kW + (size_t)l*HID*HID, kb + (size_t)l*HID,
            vW + (size_t)l*HID*384, vb + (size_t)l*384,
            qb_, kb_, vb_, N);
        k_gemm<384><<<dim3(3,(3*N+15)/16), 128, 0, stream>>>(vecb, vecW + (size_t)l*HID*384, nullptr, vecout, 3*N);
        k_edge_agg<<<N, 128, 0, stream>>>(offsets, edata, evn4, T,
                                          qb_, kb_, vb_, vecb, xab, vab);
        k_gemm<384><<<dim3(3,(N+15)/16), 128, 0, stream>>>(xab, oW + (size_t)l*HID*384, obias + (size_t)l*384, ob_, N);
        k_update<<<N, 128, 0, stream>>>(xb, vecb, ob_, vecout, vab, N);
    }

    k_final_ln<<<N, 128, 0, stream>>>(xb, onw, onb, (float*)d_out, N);
    k_copy<<<(N*384+255)/256, 256, 0, stream>>>(vecb, (float*)d_out + (size_t)N*HID, N*384);
}

// Round 3
// 1066.638 us; speedup vs baseline: 2.2942x; 1.2932x over previous
//
#include <hip/hip_runtime.h>
#include <math.h>

#define HID 128
#define NRBF 50
#define NLAYERS 6
#define CUTV 5.0f
#define KNOTS 2048            // intervals
#define TSCALE 409.6f         // KNOTS / CUTV
#define TINV   0.00244140625f // CUTV / KNOTS
#define TROWS  (KNOTS + 1)    // paired rows j=0..KNOTS
#define TSTRIDE ((size_t)TROWS * 512)

typedef unsigned int  uint32;
typedef unsigned short ushort16;

__device__ __forceinline__ float siluf(float x){ return x / (1.0f + __expf(-x)); }
__device__ __forceinline__ float lerpf(float a, float b, float f){ return fmaf(f, b - a, a); }
__device__ __forceinline__ ushort16 f2b(float x){
    uint32 u = __float_as_uint(x);
    u += 0x7fffu + ((u >> 16) & 1u);
    return (ushort16)(u >> 16);
}
__device__ __forceinline__ float b2f(ushort16 u){ return __uint_as_float(((uint32)u) << 16); }
__device__ __forceinline__ uint32 packp(float a, float b){
    return (uint32)f2b(a) | ((uint32)f2b(b) << 16);
}
__device__ __forceinline__ float plo(uint32 u){ return __uint_as_float(u << 16); }
__device__ __forceinline__ float phi(uint32 u){ return __uint_as_float(u & 0xffff0000u); }
__device__ __forceinline__ float plerp(uint32 u, float f){ float a = plo(u); return fmaf(f, phi(u) - a, a); }

// ---------------- setup: counting sort of edges by dst ----------------
__global__ void k_zero(int* p, int n){
    int i = blockIdx.x*blockDim.x + threadIdx.x;
    if (i < n) p[i] = 0;
}

__global__ void k_count(const int* ei, int E, int* counts){
    int e = blockIdx.x*blockDim.x + threadIdx.x;
    if (e < E) atomicAdd(&counts[ei[E + e]], 1);
}

__global__ void k_scan(const int* counts, int* offsets, int* cursor, int n){
    __shared__ int part[1024];
    int tid = threadIdx.x;
    int PER = (n + 1023) >> 10;
    int base = tid * PER;
    int loc[8]; int s = 0;
    #pragma unroll 8
    for (int ii = 0; ii < 8; ii++){
        if (ii < PER){
            int idx = base + ii;
            int c = (idx < n) ? counts[idx] : 0;
            loc[ii] = s; s += c;
        }
    }
    part[tid] = s;
    __syncthreads();
    for (int off = 1; off < 1024; off <<= 1){
        int v = (tid >= off) ? part[tid - off] : 0;
        __syncthreads();
        part[tid] += v;
        __syncthreads();
    }
    int excl = (tid == 0) ? 0 : part[tid - 1];
    #pragma unroll 8
    for (int ii = 0; ii < 8; ii++){
        if (ii < PER){
            int idx = base + ii;
            if (idx < n){ int o = excl + loc[ii]; offsets[idx] = o; cursor[idx] = o; }
        }
    }
    if (tid == 1023) offsets[n] = part[1023];
}

__global__ void k_scatter(const int* ei, int E, int* cursor, int* eperm){
    int e = blockIdx.x*blockDim.x + threadIdx.x;
    if (e < E){
        int d = ei[E + e];
        int pos = atomicAdd(&cursor[d], 1);
        eperm[pos] = e;
    }
}

__global__ void k_edge_vals(const int* ei, const float* edge_vec, const int* eperm, int E,
                            int4* edata, float4* evn4){
    int row = blockIdx.x*blockDim.x + threadIdx.x;
    if (row >= E) return;
    int e = eperm[row];
    int s = ei[e], d = ei[E + e];
    float vx = edge_vec[e*3+0], vy = edge_vec[e*3+1], vz = edge_vec[e*3+2];
    float ew = sqrtf(vx*vx + vy*vy + vz*vz);
    float cut = (ew < CUTV) ? 0.5f*(__cosf(ew * 0.62831853071795864f) + 1.0f) : 0.0f;
    int ns = (s != d) ? 1 : 0;
    float inv = ns ? (1.0f/ew) : 1.0f;
    float un = fminf(ew * TSCALE, (float)KNOTS);
    int j = (int)un;
    float f = un - (float)j;
    int4 ed; ed.x = s; ed.y = j; ed.z = __float_as_int(f); ed.w = __float_as_int(cut);
    edata[row] = ed;
    float4 ev; ev.x = vx*inv; ev.y = vy*inv; ev.z = vz*inv; ev.w = ns ? 1.0f : 0.0f;
    evn4[row] = ev;
}

// ---------------- tables (all 6 layers upfront, paired bf16) ----------------
__global__ __launch_bounds__(512) void k_build_tables(
    const float* means, const float* betas,
    const float* dkW, const float* dkb, const float* dvW, const float* dvb,
    uint32* Tp){
    int j = blockIdx.x, l = blockIdx.y, c = threadIdx.x;
    __shared__ float ea0[NRBF], ea1[NRBF];
    if (c < NRBF){
        float m = means[c], be = betas[c];
        float d0 = j * TINV, d1 = (j+1) * TINV;
        float c0 = (d0 < CUTV) ? 0.5f*(__cosf(d0 * 0.62831853071795864f) + 1.0f) : 0.0f;
        float c1 = (d1 < CUTV) ? 0.5f*(__cosf(d1 * 0.62831853071795864f) + 1.0f) : 0.0f;
        float u0 = __expf(-d0) - m, u1 = __expf(-d1) - m;
        ea0[c] = c0 * __expf(-be*u0*u0);
        ea1[c] = c1 * __expf(-be*u1*u1);
    }
    __syncthreads();
    float a0, a1;
    if (c < HID){
        const float* W = dkW + (size_t)l*NRBF*HID;
        a0 = a1 = dkb[(size_t)l*HID + c];
        #pragma unroll
        for (int r = 0; r < NRBF; r++){ float w = W[r*HID + c]; a0 += ea0[r]*w; a1 += ea1[r]*w; }
    } else {
        int cc = c - HID;
        const float* W = dvW + (size_t)l*NRBF*384;
        a0 = a1 = dvb[(size_t)l*384 + cc];
        #pragma unroll
        for (int r = 0; r < NRBF; r++){ float w = W[r*384 + cc]; a0 += ea0[r]*w; a1 += ea1[r]*w; }
    }
    Tp[(size_t)l*TSTRIDE + (size_t)j*512 + c] = packp(siluf(a0), siluf(a1));
}

// NE table: paired f32
__global__ __launch_bounds__(128) void k_build_ne(
    const float* means, const float* betas,
    const float* dpW, const float* dpb, float2* Tne){
    int j = blockIdx.x, c = threadIdx.x;
    __shared__ float ea0[NRBF], ea1[NRBF];
    float d0 = j * TINV, d1 = (j+1) * TINV;
    float c0 = (d0 < CUTV) ? 0.5f*(__cosf(d0 * 0.62831853071795864f) + 1.0f) : 0.0f;
    float c1 = (d1 < CUTV) ? 0.5f*(__cosf(d1 * 0.62831853071795864f) + 1.0f) : 0.0f;
    if (c < NRBF){
        float m = means[c], be = betas[c];
        float u0 = __expf(-d0) - m, u1 = __expf(-d1) - m;
        ea0[c] = c0 * __expf(-be*u0*u0);
        ea1[c] = c1 * __expf(-be*u1*u1);
    }
    __syncthreads();
    float a0 = dpb[c], a1 = a0;
    #pragma unroll
    for (int r = 0; r < NRBF; r++){ float w = dpW[r*HID + c]; a0 += ea0[r]*w; a1 += ea1[r]*w; }
    float2 o; o.x = a0*c0; o.y = a1*c1;
    Tne[(size_t)j*HID + c] = o;
}

// ---------------- neighbor embedding ----------------
__global__ __launch_bounds__(128) void k_ne_agg(
    const int* offsets, const int4* edata, const float4* evn4, const float2* Tne,
    const int* z, const float* ne_emb, float* agg){
    int i = blockIdx.x, h = threadIdx.x;
    float acc = 0.f;
    int r0 = offsets[i], r1 = offsets[i+1];
    #pragma unroll 4
    for (int row = r0; row < r1; row++){
        int4 ed = edata[row];
        int s = ed.x, j = ed.y;
        float f = __int_as_float(ed.z);
        float mask = evn4[row].w;
        float2 tv = Tne[(size_t)j*HID + h];
        float w = lerpf(tv.x, tv.y, f) * mask;
        acc += w * ne_emb[(size_t)z[s]*HID + h];
    }
    agg[(size_t)i*HID + h] = acc;
}

// combine + LN(layer0) + zero vec state/mirror
__global__ __launch_bounds__(128) void k_combine_ln(
    const int* z, const float* emb, const float* agg, const float* cbW, const float* cbb,
    const float* lnw0, const float* lnb0,
    float* x, float* hb, float* vec, ushort16* vecm, int N){
    int n0 = blockIdx.x*8, h = threadIdx.x;
    __shared__ float in_s[8][2*HID];
    int nr = min(8, N - n0);
    for (int m = 0; m < nr; m++){
        in_s[m][h]       = emb[(size_t)z[n0+m]*HID + h];
        in_s[m][HID + h] = agg[(size_t)(n0+m)*HID + h];
    }
    __syncthreads();
    float acc[8];
    #pragma unroll
    for (int m = 0; m < 8; m++) acc[m] = 0.f;
    for (int kk = 0; kk < 2*HID; kk += 4){
        float w0 = cbW[(kk+0)*HID + h], w1 = cbW[(kk+1)*HID + h];
        float w2 = cbW[(kk+2)*HID + h], w3 = cbW[(kk+3)*HID + h];
        #pragma unroll
        for (int m = 0; m < 8; m++){
            const float* a = &in_s[m][kk];
            acc[m] += a[0]*w0 + a[1]*w1 + a[2]*w2 + a[3]*w3;
        }
    }
    float bias = cbb[h], w = lnw0[h], bb = lnb0[h];
    __shared__ float r1_[2], r2_[2];
    int wid = h >> 6;
    for (int m = 0; m < nr; m++){
        int n = n0 + m;
        float v = acc[m] + bias;
        x[(size_t)n*HID + h] = v;
        float s1 = v, s2 = v*v;
        #pragma unroll
        for (int o = 32; o; o >>= 1){ s1 += __shfl_xor(s1, o, 64); s2 += __shfl_xor(s2, o, 64); }
        if ((h & 63) == 0){ r1_[wid] = s1; r2_[wid] = s2; }
        __syncthreads();
        float sum = r1_[0] + r1_[1], sumsq = r2_[0] + r2_[1];
        float mean = sum * (1.f/HID);
        float var = sumsq * (1.f/HID) - mean*mean;
        float inv = rsqrtf(var + 1e-5f);
        hb[(size_t)n*HID + h] = (v - mean)*inv*w + bb;
        __syncthreads();
        vec [(size_t)n*384 + h]       = 0.f;
        vec [(size_t)n*384 + 128 + h] = 0.f;
        vec [(size_t)n*384 + 256 + h] = 0.f;
        vecm[(size_t)n*384 + h]       = 0;
        vecm[(size_t)n*384 + 128 + h] = 0;
        vecm[(size_t)n*384 + 256 + h] = 0;
    }
}

// ---------------- fused per-layer GEMMs: q,k (mode0) | v (mode1) | vecW (mode2) ----------------
__global__ __launch_bounds__(128) void k_gemms(
    const float* __restrict__ hb, const float* __restrict__ vecb,
    const float* __restrict__ qW, const float* __restrict__ qb,
    const float* __restrict__ kW, const float* __restrict__ kb,
    const float* __restrict__ vW, const float* __restrict__ vb,
    const float* __restrict__ vecW,
    float* __restrict__ qo, ushort16* __restrict__ ko, ushort16* __restrict__ vo,
    float* __restrict__ vecout, int N){
    int NT = (N + 15) >> 4;
    int bx = blockIdx.x;
    int mode, tile;
    if (bx < NT){ mode = 0; tile = bx; }
    else if (bx < 2*NT){ mode = 1; tile = bx - NT; }
    else { mode = 2; tile = bx - 2*NT; }
    int R = (mode == 2) ? 3*N : N;
    const float* src = (mode == 2) ? vecb : hb;
    int r0 = tile*16;
    int j = threadIdx.x;
    __shared__ float in_s[16][HID];
    for (int idx = threadIdx.x; idx < 16*HID; idx += 128){
        int r = idx >> 7, kk = idx & 127;
        in_s[r][kk] = (r0 + r < R) ? src[(size_t)(r0 + r)*HID + kk] : 0.f;
    }
    __syncthreads();
    int nr = min(16, R - r0);
    if (mode == 0){
        float accq[16], acck[16];
        #pragma unroll
        for (int t = 0; t < 16; t++){ accq[t] = 0.f; acck[t] = 0.f; }
        for (int kk = 0; kk < HID; kk += 4){
            float wq0 = qW[(size_t)(kk+0)*HID + j], wq1 = qW[(size_t)(kk+1)*HID + j];
            float wq2 = qW[(size_t)(kk+2)*HID + j], wq3 = qW[(size_t)(kk+3)*HID + j];
            float wk0 = kW[(size_t)(kk+0)*HID + j], wk1 = kW[(size_t)(kk+1)*HID + j];
            float wk2 = kW[(size_t)(kk+2)*HID + j], wk3 = kW[(size_t)(kk+3)*HID + j];
            #pragma unroll
            for (int t = 0; t < 16; t++){
                float4 a = *(const float4*)&in_s[t][kk];
                accq[t] += a.x*wq0 + a.y*wq1 + a.z*wq2 + a.w*wq3;
                acck[t] += a.x*wk0 + a.y*wk1 + a.z*wk2 + a.w*wk3;
            }
        }
        float bq = qb[j], bk = kb[j];
        for (int t = 0; t < nr; t++){
            qo[(size_t)(r0+t)*HID + j] = accq[t] + bq;
            ko[(size_t)(r0+t)*HID + j] = f2b(acck[t] + bk);
        }
    } else {
        const float* W = (mode == 1) ? vW : vecW;
        float acc0[16], acc1[16], acc2[16];
        #pragma unroll
        for (int t = 0; t < 16; t++){ acc0[t] = 0.f; acc1[t] = 0.f; acc2[t] = 0.f; }
        for (int kk = 0; kk < HID; kk += 2){
            const float* w0p = W + (size_t)(kk+0)*384 + j;
            const float* w1p = W + (size_t)(kk+1)*384 + j;
            float wa0 = w0p[0], wa1 = w0p[128], wa2 = w0p[256];
            float wb0 = w1p[0], wb1 = w1p[128], wb2 = w1p[256];
            #pragma unroll
            for (int t = 0; t < 16; t++){
                float a0 = in_s[t][kk], a1 = in_s[t][kk+1];
                acc0[t] += a0*wa0 + a1*wb0;
                acc1[t] += a0*wa1 + a1*wb1;
                acc2[t] += a0*wa2 + a1*wb2;
            }
        }
        if (mode == 1){
            float b0 = vb[j], b1 = vb[j+128], b2 = vb[j+256];
            for (int t = 0; t < nr; t++){
                size_t base = (size_t)(r0+t)*384;
                vo[base + j]       = f2b(acc0[t] + b0);
                vo[base + 128 + j] = f2b(acc1[t] + b1);
                vo[base + 256 + j] = f2b(acc2[t] + b2);
            }
        } else {
            for (int t = 0; t < nr; t++){
                size_t base = (size_t)(r0+t)*384;
                vecout[base + j]       = acc0[t];
                vecout[base + 128 + j] = acc1[t];
                vecout[base + 256 + j] = acc2[t];
            }
        }
    }
}

// oW GEMM: in xab (N x 128) -> out (N x 384) f32
__global__ __launch_bounds__(128) void k_ogemm(
    const float* __restrict__ in, const float* __restrict__ W, const float* __restrict__ bias,
    float* __restrict__ out, int N){
    int r0 = blockIdx.x*16;
    int j = threadIdx.x;
    __shared__ float in_s[16][HID];
    for (int idx = threadIdx.x; idx < 16*HID; idx += 128){
        int r = idx >> 7, kk = idx & 127;
        in_s[r][kk] = (r0 + r < N) ? in[(size_t)(r0 + r)*HID + kk] : 0.f;
    }
    __syncthreads();
    float acc0[16], acc1[16], acc2[16];
    #pragma unroll
    for (int t = 0; t < 16; t++){ acc0[t] = 0.f; acc1[t] = 0.f; acc2[t] = 0.f; }
    for (int kk = 0; kk < HID; kk += 2){
        const float* w0p = W + (size_t)(kk+0)*384 + j;
        const float* w1p = W + (size_t)(kk+1)*384 + j;
        float wa0 = w0p[0], wa1 = w0p[128], wa2 = w0p[256];
        float wb0 = w1p[0], wb1 = w1p[128], wb2 = w1p[256];
        #pragma unroll
        for (int t = 0; t < 16; t++){
            float a0 = in_s[t][kk], a1 = in_s[t][kk+1];
            acc0[t] += a0*wa0 + a1*wb0;
            acc1[t] += a0*wa1 + a1*wb1;
            acc2[t] += a0*wa2 + a1*wb2;
        }
    }
    float b0 = bias[j], b1 = bias[j+128], b2 = bias[j+256];
    int nr = min(16, N - r0);
    for (int t = 0; t < nr; t++){
        size_t base = (size_t)(r0+t)*384;
        out[base + j]       = acc0[t] + b0;
        out[base + 128 + j] = acc1[t] + b1;
        out[base + 256 + j] = acc2[t] + b2;
    }
}

// ---------------- fused edge aggregation (bf16 gathers, 4-edge pipeline) ----------------
__global__ __launch_bounds__(128) void k_edge_agg(
    const int* __restrict__ offsets, const int4* __restrict__ edata,
    const float4* __restrict__ evn4, const uint32* __restrict__ Tp,
    const float* __restrict__ q, const ushort16* __restrict__ kb16,
    const ushort16* __restrict__ vb16, const ushort16* __restrict__ vecm,
    float* __restrict__ xa, float* __restrict__ va){
    int i = blockIdx.x, h = threadIdx.x;
    int head = h >> 4;
    int c0 = head*48 + (h & 15);
    float qv = q[(size_t)i*HID + h];
    float axa = 0.f, av0 = 0.f, av1 = 0.f, av2 = 0.f;
    int r0 = offsets[i], r1 = offsets[i+1];
    for (int t0 = r0; t0 < r1; t0 += 4){
        float f_[4], cut_[4], ex_[4], ey_[4], ez_[4];
        uint32 tdk_[4], tdv0_[4], tdv1_[4], tdv2_[4];
        ushort16 kv_[4], v0_[4], v1_[4], v2_[4], vc0_[4], vc1_[4], vc2_[4];
        #pragma unroll
        for (int u = 0; u < 4; u++){
            int row = min(t0 + u, r1 - 1);
            int4 ed = edata[row];
            int s = ed.x, j = ed.y;
            f_[u]   = __int_as_float(ed.z);
            cut_[u] = __int_as_float(ed.w);
            const uint32* tp = Tp + (size_t)j*512;
            tdk_[u]  = tp[h];
            tdv0_[u] = tp[128 + c0];
            tdv1_[u] = tp[144 + c0];
            tdv2_[u] = tp[160 + c0];
            kv_[u] = kb16[(size_t)s*HID + h];
            const ushort16* vr = vb16 + (size_t)s*384;
            v0_[u] = vr[c0]; v1_[u] = vr[c0+16]; v2_[u] = vr[c0+32];
            const ushort16* vc = vecm + (size_t)s*384;
            vc0_[u] = vc[h]; vc1_[u] = vc[128+h]; vc2_[u] = vc[256+h];
            float4 ev = evn4[row];
            ex_[u] = ev.x; ey_[u] = ev.y; ez_[u] = ev.z;
        }
        #pragma unroll
        for (int u = 0; u < 4; u++){
            if (t0 + u >= r1) break;
            float f = f_[u];
            float dk = plerp(tdk_[u], f);
            float p = qv * b2f(kv_[u]) * dk;
            p += __shfl_xor(p, 1, 64);
            p += __shfl_xor(p, 2, 64);
            p += __shfl_xor(p, 4, 64);
            p += __shfl_xor(p, 8, 64);
            float attn = siluf(p) * cut_[u];
            float dv0 = plerp(tdv0_[u], f);
            float dv1 = plerp(tdv1_[u], f);
            float dv2 = plerp(tdv2_[u], f);
            axa += b2f(v0_[u]) * dv0 * attn;
            float w1v = b2f(v1_[u]) * dv1;
            float w2v = b2f(v2_[u]) * dv2;
            av0 += b2f(vc0_[u])*w1v + w2v*ex_[u];
            av1 += b2f(vc1_[u])*w1v + w2v*ey_[u];
            av2 += b2f(vc2_[u])*w1v + w2v*ez_[u];
        }
    }
    xa[(size_t)i*HID + h] = axa;
    va[(size_t)i*384 + h]       = av0;
    va[(size_t)i*384 + 128 + h] = av1;
    va[(size_t)i*384 + 256 + h] = av2;
}

// ---------------- fused vecdot + residual update + next-layer LN ----------------
__global__ __launch_bounds__(128) void k_update_ln(
    float* __restrict__ x, float* __restrict__ vec, ushort16* __restrict__ vecm,
    const float* __restrict__ o, const float* __restrict__ vecout, const float* __restrict__ va,
    const float* __restrict__ lnw_n, const float* __restrict__ lnb_n,
    float* __restrict__ hb, float* __restrict__ outx, float* __restrict__ outv, int fin){
    int n = blockIdx.x, h = threadIdx.x;
    const float* vo = vecout + (size_t)n*1152;
    float vdot = vo[h]*vo[128+h] + vo[384+h]*vo[512+h] + vo[768+h]*vo[896+h];
    const float* on = o + (size_t)n*384;
    float xv = x[(size_t)n*HID + h] + vdot*on[128 + h] + on[256 + h];
    float o1 = on[h];
    size_t vb = (size_t)n*384;
    float v0 = vec[vb + h]       + vo[256  + h]*o1 + va[vb + h];
    float v1 = vec[vb + 128 + h] + vo[640  + h]*o1 + va[vb + 128 + h];
    float v2 = vec[vb + 256 + h] + vo[1024 + h]*o1 + va[vb + 256 + h];
    // LN(xv)
    float s1 = xv, s2 = xv*xv;
    #pragma unroll
    for (int oo = 32; oo; oo >>= 1){ s1 += __shfl_xor(s1, oo, 64); s2 += __shfl_xor(s2, oo, 64); }
    __shared__ float r1_[2], r2_[2];
    int wid = h >> 6;
    if ((h & 63) == 0){ r1_[wid] = s1; r2_[wid] = s2; }
    __syncthreads();
    float sum = r1_[0] + r1_[1], sumsq = r2_[0] + r2_[1];
    float mean = sum * (1.f/HID);
    float var = sumsq * (1.f/HID) - mean*mean;
    float inv = rsqrtf(var + 1e-5f);
    float lnv = (xv - mean)*inv*lnw_n[h] + lnb_n[h];
    if (!fin){
        x[(size_t)n*HID + h] = xv;
        vec[vb + h] = v0; vec[vb + 128 + h] = v1; vec[vb + 256 + h] = v2;
        vecm[vb + h] = f2b(v0); vecm[vb + 128 + h] = f2b(v1); vecm[vb + 256 + h] = f2b(v2);
        hb[(size_t)n*HID + h] = lnv;
    } else {
        outx[(size_t)n*HID + h] = lnv;
        outv[vb + h] = v0; outv[vb + 128 + h] = v1; outv[vb + 256 + h] = v2;
    }
}

// ---------------- host ----------------
extern "C" void kernel_launch(void* const* d_in, const int* in_sizes, int n_in,
                              void* d_out, int out_size, void* d_ws, size_t ws_size,
                              hipStream_t stream){
    const int*   z        = (const int*)  d_in[0];
    const int*   ei       = (const int*)  d_in[1];
    const float* edge_vec = (const float*)d_in[2];
    const float* emb      = (const float*)d_in[3];
    const float* means    = (const float*)d_in[4];
    const float* betas    = (const float*)d_in[5];
    const float* ne_emb   = (const float*)d_in[6];
    const float* dpW      = (const float*)d_in[7];
    const float* dpb      = (const float*)d_in[8];
    const float* cbW      = (const float*)d_in[9];
    const float* cbb      = (const float*)d_in[10];
    const float* lnw      = (const float*)d_in[11];
    const float* lnb      = (const float*)d_in[12];
    const float* qW       = (const float*)d_in[13];
    const float* qb       = (const float*)d_in[14];
    const float* kW       = (const float*)d_in[15];
    const float* kb       = (const float*)d_in[16];
    const float* vW       = (const float*)d_in[17];
    const float* vb       = (const float*)d_in[18];
    const float* oW       = (const float*)d_in[19];
    const float* obias    = (const float*)d_in[20];
    const float* vecW     = (const float*)d_in[21];
    const float* dkW      = (const float*)d_in[22];
    const float* dkb      = (const float*)d_in[23];
    const float* dvW      = (const float*)d_in[24];
    const float* dvb      = (const float*)d_in[25];
    const float* onw      = (const float*)d_in[26];
    const float* onb      = (const float*)d_in[27];

    int N = in_sizes[0];
    int E = in_sizes[1] / 2;

    char* p = (char*)d_ws;
    auto alloc = [&](size_t bytes){ void* r = (void*)p; p += (bytes + 255) & ~(size_t)255; return r; };
    int*      counts  = (int*)     alloc((size_t)N*4);
    int*      offsets = (int*)     alloc((size_t)(N+1)*4);
    int*      cursor  = (int*)     alloc((size_t)N*4);
    int*      eperm   = (int*)     alloc((size_t)E*4);
    int4*     edata   = (int4*)    alloc((size_t)E*16);
    float4*   evn4    = (float4*)  alloc((size_t)E*16);
    uint32*   Tp      = (uint32*)  alloc((size_t)NLAYERS*TSTRIDE*4);
    float2*   Tne     = (float2*)  alloc((size_t)TROWS*HID*8);
    float*    agg     = (float*)   alloc((size_t)N*HID*4);
    float*    xb      = (float*)   alloc((size_t)N*HID*4);
    float*    hb      = (float*)   alloc((size_t)N*HID*4);
    float*    qb_     = (float*)   alloc((size_t)N*HID*4);
    ushort16* kb16    = (ushort16*)alloc((size_t)N*HID*2);
    ushort16* vb16    = (ushort16*)alloc((size_t)N*384*2);
    ushort16* vecm    = (ushort16*)alloc((size_t)N*384*2);
    float*    vecb    = (float*)   alloc((size_t)N*384*4);
    float*    vecout  = (float*)   alloc((size_t)N*1152*4);
    float*    xab     = (float*)   alloc((size_t)N*HID*4);
    float*    vab     = (float*)   alloc((size_t)N*384*4);
    float*    ob_     = (float*)   alloc((size_t)N*384*4);

    k_zero<<<(N+255)/256, 256, 0, stream>>>(counts, N);
    k_count<<<(E+255)/256, 256, 0, stream>>>(ei, E, counts);
    k_scan<<<1, 1024, 0, stream>>>(counts, offsets, cursor, N);
    k_scatter<<<(E+255)/256, 256, 0, stream>>>(ei, E, cursor, eperm);
    k_edge_vals<<<(E+255)/256, 256, 0, stream>>>(ei, edge_vec, eperm, E, edata, evn4);

    k_build_tables<<<dim3(TROWS, NLAYERS), 512, 0, stream>>>(means, betas, dkW, dkb, dvW, dvb, Tp);
    k_build_ne<<<TROWS, 128, 0, stream>>>(means, betas, dpW, dpb, Tne);
    k_ne_agg<<<N, 128, 0, stream>>>(offsets, edata, evn4, Tne, z, ne_emb, agg);
    k_combine_ln<<<(N+7)/8, 128, 0, stream>>>(z, emb, agg, cbW, cbb, lnw, lnb,
                                              xb, hb, vecb, vecm, N);

    int NT = (N + 15) >> 4;
    int NT3 = (3*N + 15) >> 4;
    float* outx = (float*)d_out;
    float* outv = (float*)d_out + (size_t)N*HID;

    for (int l = 0; l < NLAYERS; l++){
        k_gemms<<<2*NT + NT3, 128, 0, stream>>>(hb, vecb,
            qW + (size_t)l*HID*HID, qb + (size_t)l*HID,
            kW + (size_t)l*HID*HID, kb + (size_t)l*HID,
            vW + (size_t)l*HID*384, vb + (size_t)l*384,
            vecW + (size_t)l*HID*384,
            qb_, kb16, vb16, vecout, N);
        k_edge_agg<<<N, 128, 0, stream>>>(offsets, edata, evn4, Tp + (size_t)l*TSTRIDE,
                                          qb_, kb16, vb16, vecm, xab, vab);
        k_ogemm<<<NT, 128, 0, stream>>>(xab, oW + (size_t)l*HID*384, obias + (size_t)l*384, ob_, N);
        int fin = (l == NLAYERS-1);
        k_update_ln<<<N, 128, 0, stream>>>(xb, vecb, vecm, ob_, vecout, vab,
            fin ? onw : lnw + (size_t)(l+1)*HID,
            fin ? onb : lnb + (size_t)(l+1)*HID,
            hb, outx, outv, fin);
    }
}

// Round 4
// 761.706 us; speedup vs baseline: 3.2127x; 1.4003x over previous
//
#include <hip/hip_runtime.h>
#include <math.h>

#define HID 128
#define NRBF 50
#define NLAYERS 6
#define CUTV 5.0f
#define KNOTS 2048            // intervals
#define TSCALE 409.6f         // KNOTS / CUTV
#define TINV   0.00244140625f // CUTV / KNOTS
#define TROWS  (KNOTS + 1)    // paired rows j=0..KNOTS
#define TSTRIDE ((size_t)TROWS * 512)
#define WCOLS 1408            // 128 q | 128 k | 384 v | 384 vecW | 384 oW

typedef unsigned int  uint32;
typedef unsigned short ushort16;
typedef __attribute__((ext_vector_type(8))) short short8;
typedef __attribute__((ext_vector_type(4))) float f32x4;

__device__ __forceinline__ float siluf(float x){ return x / (1.0f + __expf(-x)); }
__device__ __forceinline__ float lerpf(float a, float b, float f){ return fmaf(f, b - a, a); }
__device__ __forceinline__ ushort16 f2b(float x){
    uint32 u = __float_as_uint(x);
    u += 0x7fffu + ((u >> 16) & 1u);
    return (ushort16)(u >> 16);
}
__device__ __forceinline__ float b2f(ushort16 u){ return __uint_as_float(((uint32)u) << 16); }
__device__ __forceinline__ uint32 packp(float a, float b){
    return (uint32)f2b(a) | ((uint32)f2b(b) << 16);
}
__device__ __forceinline__ float plo(uint32 u){ return __uint_as_float(u << 16); }
__device__ __forceinline__ float phi(uint32 u){ return __uint_as_float(u & 0xffff0000u); }
__device__ __forceinline__ float plerp(uint32 u, float f){ float a = plo(u); return fmaf(f, phi(u) - a, a); }

// ---------------- setup: counting sort of edges by dst ----------------
__global__ void k_zero(int* p, int n){
    int i = blockIdx.x*blockDim.x + threadIdx.x;
    if (i < n) p[i] = 0;
}

__global__ void k_count(const int* ei, int E, int* counts){
    int e = blockIdx.x*blockDim.x + threadIdx.x;
    if (e < E) atomicAdd(&counts[ei[E + e]], 1);
}

__global__ void k_scan(const int* counts, int* offsets, int* cursor, int n){
    __shared__ int part[1024];
    int tid = threadIdx.x;
    int PER = (n + 1023) >> 10;
    int base = tid * PER;
    int loc[8]; int s = 0;
    #pragma unroll 8
    for (int ii = 0; ii < 8; ii++){
        if (ii < PER){
            int idx = base + ii;
            int c = (idx < n) ? counts[idx] : 0;
            loc[ii] = s; s += c;
        }
    }
    part[tid] = s;
    __syncthreads();
    for (int off = 1; off < 1024; off <<= 1){
        int v = (tid >= off) ? part[tid - off] : 0;
        __syncthreads();
        part[tid] += v;
        __syncthreads();
    }
    int excl = (tid == 0) ? 0 : part[tid - 1];
    #pragma unroll 8
    for (int ii = 0; ii < 8; ii++){
        if (ii < PER){
            int idx = base + ii;
            if (idx < n){ int o = excl + loc[ii]; offsets[idx] = o; cursor[idx] = o; }
        }
    }
    if (tid == 1023) offsets[n] = part[1023];
}

__global__ void k_scatter(const int* ei, int E, int* cursor, int* eperm){
    int e = blockIdx.x*blockDim.x + threadIdx.x;
    if (e < E){
        int d = ei[E + e];
        int pos = atomicAdd(&cursor[d], 1);
        eperm[pos] = e;
    }
}

__global__ void k_edge_vals(const int* ei, const float* edge_vec, const int* eperm, int E,
                            int4* edata, float4* evn4){
    int row = blockIdx.x*blockDim.x + threadIdx.x;
    if (row >= E) return;
    int e = eperm[row];
    int s = ei[e], d = ei[E + e];
    float vx = edge_vec[e*3+0], vy = edge_vec[e*3+1], vz = edge_vec[e*3+2];
    float ew = sqrtf(vx*vx + vy*vy + vz*vz);
    float cut = (ew < CUTV) ? 0.5f*(__cosf(ew * 0.62831853071795864f) + 1.0f) : 0.0f;
    int ns = (s != d) ? 1 : 0;
    float inv = ns ? (1.0f/ew) : 1.0f;
    float un = fminf(ew * TSCALE, (float)KNOTS);
    int j = (int)un;
    float f = un - (float)j;
    int4 ed; ed.x = s; ed.y = j; ed.z = __float_as_int(f); ed.w = __float_as_int(cut);
    edata[row] = ed;
    float4 ev; ev.x = vx*inv; ev.y = vy*inv; ev.z = vz*inv; ev.w = ns ? 1.0f : 0.0f;
    evn4[row] = ev;
}

// zero pad rows of bf16 activation buffers (rows N..Nup / 3N..N3up)
__global__ void k_pad(ushort16* hb16, ushort16* vecm, ushort16* xab16, int N, int Nup, int N3up){
    int i = blockIdx.x*blockDim.x + threadIdx.x;
    int hpad = (Nup - N)*HID;
    int vpad = (N3up - 3*N)*HID;
    if (i < hpad){ hb16[(size_t)N*HID + i] = 0; xab16[(size_t)N*HID + i] = 0; }
    if (i < vpad) vecm[(size_t)3*N*HID + i] = 0;
}

// ---------------- tables (all 6 layers upfront, paired bf16) ----------------
__global__ __launch_bounds__(512) void k_build_tables(
    const float* means, const float* betas,
    const float* dkW, const float* dkb, const float* dvW, const float* dvb,
    uint32* Tp){
    int j = blockIdx.x, l = blockIdx.y, c = threadIdx.x;
    __shared__ float ea0[NRBF], ea1[NRBF];
    if (c < NRBF){
        float m = means[c], be = betas[c];
        float d0 = j * TINV, d1 = (j+1) * TINV;
        float c0 = (d0 < CUTV) ? 0.5f*(__cosf(d0 * 0.62831853071795864f) + 1.0f) : 0.0f;
        float c1 = (d1 < CUTV) ? 0.5f*(__cosf(d1 * 0.62831853071795864f) + 1.0f) : 0.0f;
        float u0 = __expf(-d0) - m, u1 = __expf(-d1) - m;
        ea0[c] = c0 * __expf(-be*u0*u0);
        ea1[c] = c1 * __expf(-be*u1*u1);
    }
    __syncthreads();
    float a0, a1;
    if (c < HID){
        const float* W = dkW + (size_t)l*NRBF*HID;
        a0 = a1 = dkb[(size_t)l*HID + c];
        #pragma unroll
        for (int r = 0; r < NRBF; r++){ float w = W[r*HID + c]; a0 += ea0[r]*w; a1 += ea1[r]*w; }
    } else {
        int cc = c - HID;
        const float* W = dvW + (size_t)l*NRBF*384;
        a0 = a1 = dvb[(size_t)l*384 + cc];
        #pragma unroll
        for (int r = 0; r < NRBF; r++){ float w = W[r*384 + cc]; a0 += ea0[r]*w; a1 += ea1[r]*w; }
    }
    Tp[(size_t)l*TSTRIDE + (size_t)j*512 + c] = packp(siluf(a0), siluf(a1));
}

// NE table: paired f32
__global__ __launch_bounds__(128) void k_build_ne(
    const float* means, const float* betas,
    const float* dpW, const float* dpb, float2* Tne){
    int j = blockIdx.x, c = threadIdx.x;
    __shared__ float ea0[NRBF], ea1[NRBF];
    float d0 = j * TINV, d1 = (j+1) * TINV;
    float c0 = (d0 < CUTV) ? 0.5f*(__cosf(d0 * 0.62831853071795864f) + 1.0f) : 0.0f;
    float c1 = (d1 < CUTV) ? 0.5f*(__cosf(d1 * 0.62831853071795864f) + 1.0f) : 0.0f;
    if (c < NRBF){
        float m = means[c], be = betas[c];
        float u0 = __expf(-d0) - m, u1 = __expf(-d1) - m;
        ea0[c] = c0 * __expf(-be*u0*u0);
        ea1[c] = c1 * __expf(-be*u1*u1);
    }
    __syncthreads();
    float a0 = dpb[c], a1 = a0;
    #pragma unroll
    for (int r = 0; r < NRBF; r++){ float w = dpW[r*HID + c]; a0 += ea0[r]*w; a1 += ea1[r]*w; }
    float2 o; o.x = a0*c0; o.y = a1*c1;
    Tne[(size_t)j*HID + c] = o;
}

// ---------------- weight transpose: WT[l][col][k] bf16, cols: q|k|v|vecW|oW ----------------
__global__ __launch_bounds__(256) void k_build_wt(
    const float* qW, const float* kW, const float* vW, const float* vecW, const float* oW,
    ushort16* WT){
    int l = blockIdx.y; int c0 = blockIdx.x*32;
    const float* W; int C; int cs;
    if (c0 < 128)      { W = qW   + (size_t)l*HID*128; C = 128; cs = c0; }
    else if (c0 < 256) { W = kW   + (size_t)l*HID*128; C = 128; cs = c0-128; }
    else if (c0 < 640) { W = vW   + (size_t)l*HID*384; C = 384; cs = c0-256; }
    else if (c0 < 1024){ W = vecW + (size_t)l*HID*384; C = 384; cs = c0-640; }
    else               { W = oW   + (size_t)l*HID*384; C = 384; cs = c0-1024; }
    __shared__ ushort16 t[128][33];
    for (int i = threadIdx.x; i < 128*32; i += 256){
        int k = i >> 5, c = i & 31;
        t[k][c] = f2b(W[(size_t)k*C + cs + c]);
    }
    __syncthreads();
    ushort16* dst = WT + (size_t)l*WCOLS*HID + (size_t)c0*HID;
    for (int i = threadIdx.x; i < 128*32; i += 256){
        int c = i >> 7, k = i & 127;
        dst[(size_t)c*HID + k] = t[k][c];
    }
}

// ---------------- MFMA GEMMs ----------------
// merged qkv (A=hb16, 640 cols) + vecW (A=vecm, 384 cols): grid (16, ceil(3N/64))
__global__ __launch_bounds__(256) void k_mfma01(
    const ushort16* __restrict__ hb16, const ushort16* __restrict__ vecm,
    const ushort16* __restrict__ WT,
    const float* __restrict__ qbias, const float* __restrict__ kbias, const float* __restrict__ vbias,
    float* __restrict__ qo, ushort16* __restrict__ ko, ushort16* __restrict__ vo,
    float* __restrict__ vecout, int N){
    int cg = blockIdx.x;
    int rblk = blockIdx.y*64;
    const ushort16* A; int R; int cblk; const ushort16* wt;
    if (cg < 10){ A = hb16; R = N;   cblk = cg*64;      wt = WT; }
    else        { A = vecm; R = 3*N; cblk = (cg-10)*64; wt = WT + (size_t)640*HID; }
    if (rblk >= R) return;
    int wave = threadIdx.x >> 6, lane = threadIdx.x & 63;
    int r0 = rblk + wave*16;
    int l16 = lane & 15, lg = lane >> 4;
    short8 a[4];
    const ushort16* ar = A + (size_t)(r0 + l16)*HID + lg*8;
    #pragma unroll
    for (int ks = 0; ks < 4; ks++) a[ks] = *(const short8*)(ar + ks*32);
    f32x4 acc[4];
    #pragma unroll
    for (int ct = 0; ct < 4; ct++){ acc[ct][0]=0.f; acc[ct][1]=0.f; acc[ct][2]=0.f; acc[ct][3]=0.f; }
    #pragma unroll
    for (int ct = 0; ct < 4; ct++){
        const ushort16* br = wt + (size_t)(cblk + ct*16 + l16)*HID + lg*8;
        #pragma unroll
        for (int ks = 0; ks < 4; ks++){
            short8 b = *(const short8*)(br + ks*32);
            acc[ct] = __builtin_amdgcn_mfma_f32_16x16x32_bf16(a[ks], b, acc[ct], 0, 0, 0);
        }
    }
    #pragma unroll
    for (int ct = 0; ct < 4; ct++){
        int gc = cblk + ct*16 + l16;
        #pragma unroll
        for (int rg = 0; rg < 4; rg++){
            int row = r0 + lg*4 + rg;
            if (row >= R) continue;
            float v = acc[ct][rg];
            if (cg < 10){
                if (gc < 128)      qo[(size_t)row*HID + gc]       = v + qbias[gc];
                else if (gc < 256) ko[(size_t)row*HID + (gc-128)] = f2b(v + kbias[gc-128]);
                else               vo[(size_t)row*384 + (gc-256)] = f2b(v + vbias[gc-256]);
            } else {
                vecout[(size_t)row*384 + gc] = v;
            }
        }
    }
}

// oW GEMM: A=xab16 (N x 128 bf16) -> ob_ (N x 384 f32): grid (6, ceil(N/64))
__global__ __launch_bounds__(256) void k_mfma_o(
    const ushort16* __restrict__ A, const ushort16* __restrict__ WT,
    const float* __restrict__ bias, float* __restrict__ out, int N){
    int cblk = blockIdx.x*64;
    int rblk = blockIdx.y*64;
    if (rblk >= N) return;
    int wave = threadIdx.x >> 6, lane = threadIdx.x & 63;
    int r0 = rblk + wave*16;
    int l16 = lane & 15, lg = lane >> 4;
    short8 a[4];
    const ushort16* ar = A + (size_t)(r0 + l16)*HID + lg*8;
    #pragma unroll
    for (int ks = 0; ks < 4; ks++) a[ks] = *(const short8*)(ar + ks*32);
    f32x4 acc[4];
    #pragma unroll
    for (int ct = 0; ct < 4; ct++){ acc[ct][0]=0.f; acc[ct][1]=0.f; acc[ct][2]=0.f; acc[ct][3]=0.f; }
    const ushort16* wt = WT + (size_t)1024*HID;
    #pragma unroll
    for (int ct = 0; ct < 4; ct++){
        const ushort16* br = wt + (size_t)(cblk + ct*16 + l16)*HID + lg*8;
        #pragma unroll
        for (int ks = 0; ks < 4; ks++){
            short8 b = *(const short8*)(br + ks*32);
            acc[ct] = __builtin_amdgcn_mfma_f32_16x16x32_bf16(a[ks], b, acc[ct], 0, 0, 0);
        }
    }
    #pragma unroll
    for (int ct = 0; ct < 4; ct++){
        int gc = cblk + ct*16 + l16;
        float bb = bias[gc];
        #pragma unroll
        for (int rg = 0; rg < 4; rg++){
            int row = r0 + lg*4 + rg;
            if (row >= N) continue;
            out[(size_t)row*384 + gc] = acc[ct][rg] + bb;
        }
    }
}

// ---------------- neighbor embedding ----------------
__global__ __launch_bounds__(128) void k_ne_agg(
    const int* offsets, const int4* edata, const float4* evn4, const float2* Tne,
    const int* z, const float* ne_emb, float* agg){
    int i = blockIdx.x, h = threadIdx.x;
    float acc = 0.f;
    int r0 = offsets[i], r1 = offsets[i+1];
    #pragma unroll 4
    for (int row = r0; row < r1; row++){
        int4 ed = edata[row];
        int s = ed.x, j = ed.y;
        float f = __int_as_float(ed.z);
        float mask = evn4[row].w;
        float2 tv = Tne[(size_t)j*HID + h];
        float w = lerpf(tv.x, tv.y, f) * mask;
        acc += w * ne_emb[(size_t)z[s]*HID + h];
    }
    agg[(size_t)i*HID + h] = acc;
}

// combine + LN(layer0) + zero vec state/mirror; hb16 output
__global__ __launch_bounds__(128) void k_combine_ln(
    const int* z, const float* emb, const float* agg, const float* cbW, const float* cbb,
    const float* lnw0, const float* lnb0,
    float* x, ushort16* hb16, float* vec, ushort16* vecm, int N){
    int n0 = blockIdx.x*8, h = threadIdx.x;
    __shared__ float in_s[8][2*HID];
    int nr = min(8, N - n0);
    for (int m = 0; m < nr; m++){
        in_s[m][h]       = emb[(size_t)z[n0+m]*HID + h];
        in_s[m][HID + h] = agg[(size_t)(n0+m)*HID + h];
    }
    __syncthreads();
    float acc[8];
    #pragma unroll
    for (int m = 0; m < 8; m++) acc[m] = 0.f;
    for (int kk = 0; kk < 2*HID; kk += 4){
        float w0 = cbW[(kk+0)*HID + h], w1 = cbW[(kk+1)*HID + h];
        float w2 = cbW[(kk+2)*HID + h], w3 = cbW[(kk+3)*HID + h];
        #pragma unroll
        for (int m = 0; m < 8; m++){
            const float* a = &in_s[m][kk];
            acc[m] += a[0]*w0 + a[1]*w1 + a[2]*w2 + a[3]*w3;
        }
    }
    float bias = cbb[h], w = lnw0[h], bb = lnb0[h];
    __shared__ float r1_[2], r2_[2];
    int wid = h >> 6;
    for (int m = 0; m < nr; m++){
        int n = n0 + m;
        float v = acc[m] + bias;
        x[(size_t)n*HID + h] = v;
        float s1 = v, s2 = v*v;
        #pragma unroll
        for (int o = 32; o; o >>= 1){ s1 += __shfl_xor(s1, o, 64); s2 += __shfl_xor(s2, o, 64); }
        if ((h & 63) == 0){ r1_[wid] = s1; r2_[wid] = s2; }
        __syncthreads();
        float sum = r1_[0] + r1_[1], sumsq = r2_[0] + r2_[1];
        float mean = sum * (1.f/HID);
        float var = sumsq * (1.f/HID) - mean*mean;
        float inv = rsqrtf(var + 1e-5f);
        hb16[(size_t)n*HID + h] = f2b((v - mean)*inv*w + bb);
        __syncthreads();
        vec [(size_t)n*384 + h]       = 0.f;
        vec [(size_t)n*384 + 128 + h] = 0.f;
        vec [(size_t)n*384 + 256 + h] = 0.f;
        vecm[(size_t)n*384 + h]       = 0;
        vecm[(size_t)n*384 + 128 + h] = 0;
        vecm[(size_t)n*384 + 256 + h] = 0;
    }
}

// ---------------- fused edge aggregation (bf16 gathers, 4-edge pipeline) ----------------
__global__ __launch_bounds__(128) void k_edge_agg(
    const int* __restrict__ offsets, const int4* __restrict__ edata,
    const float4* __restrict__ evn4, const uint32* __restrict__ Tp,
    const float* __restrict__ q, const ushort16* __restrict__ kb16,
    const ushort16* __restrict__ vb16, const ushort16* __restrict__ vecm,
    ushort16* __restrict__ xa16, float* __restrict__ va){
    int i = blockIdx.x, h = threadIdx.x;
    int head = h >> 4;
    int c0 = head*48 + (h & 15);
    float qv = q[(size_t)i*HID + h];
    float axa = 0.f, av0 = 0.f, av1 = 0.f, av2 = 0.f;
    int r0 = offsets[i], r1 = offsets[i+1];
    for (int t0 = r0; t0 < r1; t0 += 4){
        float f_[4], cut_[4], ex_[4], ey_[4], ez_[4];
        uint32 tdk_[4], tdv0_[4], tdv1_[4], tdv2_[4];
        ushort16 kv_[4], v0_[4], v1_[4], v2_[4], vc0_[4], vc1_[4], vc2_[4];
        #pragma unroll
        for (int u = 0; u < 4; u++){
            int row = min(t0 + u, r1 - 1);
            int4 ed = edata[row];
            int s = ed.x, j = ed.y;
            f_[u]   = __int_as_float(ed.z);
            cut_[u] = __int_as_float(ed.w);
            const uint32* tp = Tp + (size_t)j*512;
            tdk_[u]  = tp[h];
            tdv0_[u] = tp[128 + c0];
            tdv1_[u] = tp[144 + c0];
            tdv2_[u] = tp[160 + c0];
            kv_[u] = kb16[(size_t)s*HID + h];
            const ushort16* vr = vb16 + (size_t)s*384;
            v0_[u] = vr[c0]; v1_[u] = vr[c0+16]; v2_[u] = vr[c0+32];
            const ushort16* vc = vecm + (size_t)s*384;
            vc0_[u] = vc[h]; vc1_[u] = vc[128+h]; vc2_[u] = vc[256+h];
            float4 ev = evn4[row];
            ex_[u] = ev.x; ey_[u] = ev.y; ez_[u] = ev.z;
        }
        #pragma unroll
        for (int u = 0; u < 4; u++){
            if (t0 + u >= r1) break;
            float f = f_[u];
            float dk = plerp(tdk_[u], f);
            float p = qv * b2f(kv_[u]) * dk;
            p += __shfl_xor(p, 1, 64);
            p += __shfl_xor(p, 2, 64);
            p += __shfl_xor(p, 4, 64);
            p += __shfl_xor(p, 8, 64);
            float attn = siluf(p) * cut_[u];
            float dv0 = plerp(tdv0_[u], f);
            float dv1 = plerp(tdv1_[u], f);
            float dv2 = plerp(tdv2_[u], f);
            axa += b2f(v0_[u]) * dv0 * attn;
            float w1v = b2f(v1_[u]) * dv1;
            float w2v = b2f(v2_[u]) * dv2;
            av0 += b2f(vc0_[u])*w1v + w2v*ex_[u];
            av1 += b2f(vc1_[u])*w1v + w2v*ey_[u];
            av2 += b2f(vc2_[u])*w1v + w2v*ez_[u];
        }
    }
    xa16[(size_t)i*HID + h] = f2b(axa);
    va[(size_t)i*384 + h]       = av0;
    va[(size_t)i*384 + 128 + h] = av1;
    va[(size_t)i*384 + 256 + h] = av2;
}

// ---------------- fused vecdot + residual update + next-layer LN ----------------
__global__ __launch_bounds__(128) void k_update_ln(
    float* __restrict__ x, float* __restrict__ vec, ushort16* __restrict__ vecm,
    const float* __restrict__ o, const float* __restrict__ vecout, const float* __restrict__ va,
    const float* __restrict__ lnw_n, const float* __restrict__ lnb_n,
    ushort16* __restrict__ hb16, float* __restrict__ outx, float* __restrict__ outv, int fin){
    int n = blockIdx.x, h = threadIdx.x;
    const float* vo = vecout + (size_t)n*1152;
    float vdot = vo[h]*vo[128+h] + vo[384+h]*vo[512+h] + vo[768+h]*vo[896+h];
    const float* on = o + (size_t)n*384;
    float xv = x[(size_t)n*HID + h] + vdot*on[128 + h] + on[256 + h];
    float o1 = on[h];
    size_t vb = (size_t)n*384;
    float v0 = vec[vb + h]       + vo[256  + h]*o1 + va[vb + h];
    float v1 = vec[vb + 128 + h] + vo[640  + h]*o1 + va[vb + 128 + h];
    float v2 = vec[vb + 256 + h] + vo[1024 + h]*o1 + va[vb + 256 + h];
    float s1 = xv, s2 = xv*xv;
    #pragma unroll
    for (int oo = 32; oo; oo >>= 1){ s1 += __shfl_xor(s1, oo, 64); s2 += __shfl_xor(s2, oo, 64); }
    __shared__ float r1_[2], r2_[2];
    int wid = h >> 6;
    if ((h & 63) == 0){ r1_[wid] = s1; r2_[wid] = s2; }
    __syncthreads();
    float sum = r1_[0] + r1_[1], sumsq = r2_[0] + r2_[1];
    float mean = sum * (1.f/HID);
    float var = sumsq * (1.f/HID) - mean*mean;
    float inv = rsqrtf(var + 1e-5f);
    float lnv = (xv - mean)*inv*lnw_n[h] + lnb_n[h];
    if (!fin){
        x[(size_t)n*HID + h] = xv;
        vec[vb + h] = v0; vec[vb + 128 + h] = v1; vec[vb + 256 + h] = v2;
        vecm[vb + h] = f2b(v0); vecm[vb + 128 + h] = f2b(v1); vecm[vb + 256 + h] = f2b(v2);
        hb16[(size_t)n*HID + h] = f2b(lnv);
    } else {
        outx[(size_t)n*HID + h] = lnv;
        outv[vb + h] = v0; outv[vb + 128 + h] = v1; outv[vb + 256 + h] = v2;
    }
}

// ---------------- host ----------------
extern "C" void kernel_launch(void* const* d_in, const int* in_sizes, int n_in,
                              void* d_out, int out_size, void* d_ws, size_t ws_size,
                              hipStream_t stream){
    const int*   z        = (const int*)  d_in[0];
    const int*   ei       = (const int*)  d_in[1];
    const float* edge_vec = (const float*)d_in[2];
    const float* emb      = (const float*)d_in[3];
    const float* means    = (const float*)d_in[4];
    const float* betas    = (const float*)d_in[5];
    const float* ne_emb   = (const float*)d_in[6];
    const float* dpW      = (const float*)d_in[7];
    const float* dpb      = (const float*)d_in[8];
    const float* cbW      = (const float*)d_in[9];
    const float* cbb      = (const float*)d_in[10];
    const float* lnw      = (const float*)d_in[11];
    const float* lnb      = (const float*)d_in[12];
    const float* qW       = (const float*)d_in[13];
    const float* qb       = (const float*)d_in[14];
    const float* kW       = (const float*)d_in[15];
    const float* kb       = (const float*)d_in[16];
    const float* vW       = (const float*)d_in[17];
    const float* vb       = (const float*)d_in[18];
    const float* oW       = (const float*)d_in[19];
    const float* obias    = (const float*)d_in[20];
    const float* vecW     = (const float*)d_in[21];
    const float* dkW      = (const float*)d_in[22];
    const float* dkb      = (const float*)d_in[23];
    const float* dvW      = (const float*)d_in[24];
    const float* dvb      = (const float*)d_in[25];
    const float* onw      = (const float*)d_in[26];
    const float* onb      = (const float*)d_in[27];

    int N = in_sizes[0];
    int E = in_sizes[1] / 2;
    int Nup  = ((N + 63) >> 6) << 6;
    int N3up = ((3*N + 63) >> 6) << 6;

    char* p = (char*)d_ws;
    auto alloc = [&](size_t bytes){ void* r = (void*)p; p += (bytes + 255) & ~(size_t)255; return r; };
    int*      counts  = (int*)     alloc((size_t)N*4);
    int*      offsets = (int*)     alloc((size_t)(N+1)*4);
    int*      cursor  = (int*)     alloc((size_t)N*4);
    int*      eperm   = (int*)     alloc((size_t)E*4);
    int4*     edata   = (int4*)    alloc((size_t)E*16);
    float4*   evn4    = (float4*)  alloc((size_t)E*16);
    uint32*   Tp      = (uint32*)  alloc((size_t)NLAYERS*TSTRIDE*4);
    float2*   Tne     = (float2*)  alloc((size_t)TROWS*HID*8);
    ushort16* WT      = (ushort16*)alloc((size_t)NLAYERS*WCOLS*HID*2);
    float*    agg     = (float*)   alloc((size_t)N*HID*4);
    float*    xb      = (float*)   alloc((size_t)N*HID*4);
    ushort16* hb16    = (ushort16*)alloc((size_t)Nup*HID*2);
    float*    qb_     = (float*)   alloc((size_t)N*HID*4);
    ushort16* kb16    = (ushort16*)alloc((size_t)N*HID*2);
    ushort16* vb16    = (ushort16*)alloc((size_t)N*384*2);
    ushort16* vecm    = (ushort16*)alloc((size_t)N3up*HID*2);
    float*    vecb    = (float*)   alloc((size_t)N*384*4);
    float*    vecout  = (float*)   alloc((size_t)N*1152*4);
    ushort16* xab16   = (ushort16*)alloc((size_t)Nup*HID*2);
    float*    vab     = (float*)   alloc((size_t)N*384*4);
    float*    ob_     = (float*)   alloc((size_t)N*384*4);

    k_zero<<<(N+255)/256, 256, 0, stream>>>(counts, N);
    k_count<<<(E+255)/256, 256, 0, stream>>>(ei, E, counts);
    k_scan<<<1, 1024, 0, stream>>>(counts, offsets, cursor, N);
    k_scatter<<<(E+255)/256, 256, 0, stream>>>(ei, E, cursor, eperm);
    k_edge_vals<<<(E+255)/256, 256, 0, stream>>>(ei, edge_vec, eperm, E, edata, evn4);
    k_pad<<<((Nup-N)*HID + (N3up-3*N)*HID + 255)/256 + 1, 256, 0, stream>>>(hb16, vecm, xab16, N, Nup, N3up);

    k_build_tables<<<dim3(TROWS, NLAYERS), 512, 0, stream>>>(means, betas, dkW, dkb, dvW, dvb, Tp);
    k_build_ne<<<TROWS, 128, 0, stream>>>(means, betas, dpW, dpb, Tne);
    k_build_wt<<<dim3(WCOLS/32, NLAYERS), 256, 0, stream>>>(qW, kW, vW, vecW, oW, WT);
    k_ne_agg<<<N, 128, 0, stream>>>(offsets, edata, evn4, Tne, z, ne_emb, agg);
    k_combine_ln<<<(N+7)/8, 128, 0, stream>>>(z, emb, agg, cbW, cbb, lnw, lnb,
                                              xb, hb16, vecb, vecm, N);

    float* outx = (float*)d_out;
    float* outv = (float*)d_out + (size_t)N*HID;

    for (int l = 0; l < NLAYERS; l++){
        const ushort16* WTl = WT + (size_t)l*WCOLS*HID;
        k_mfma01<<<dim3(16, (3*N+63)/64), 256, 0, stream>>>(hb16, vecm, WTl,
            qb + (size_t)l*HID, kb + (size_t)l*HID, vb + (size_t)l*384,
            qb_, kb16, vb16, vecout, N);
        k_edge_agg<<<N, 128, 0, stream>>>(offsets, edata, evn4, Tp + (size_t)l*TSTRIDE,
                                          qb_, kb16, vb16, vecm, xab16, vab);
        k_mfma_o<<<dim3(6, (N+63)/64), 256, 0, stream>>>(xab16, WTl, obias + (size_t)l*384, ob_, N);
        int fin = (l == NLAYERS-1);
        k_update_ln<<<N, 128, 0, stream>>>(xb, vecb, vecm, ob_, vecout, vab,
            fin ? onw : lnw + (size_t)(l+1)*HID,
            fin ? onb : lnb + (size_t)(l+1)*HID,
            hb16, outx, outv, fin);
    }
}

// Round 5
// 682.634 us; speedup vs baseline: 3.5848x; 1.1158x over previous
//
#include <hip/hip_runtime.h>
#include <math.h>

#define HID 128
#define NRBF 50
#define NLAYERS 6
#define CUTV 5.0f
#define KNOTS 1024            // intervals
#define TSCALE 204.8f         // KNOTS / CUTV
#define TINV   0.0048828125f  // CUTV / KNOTS
#define TROWS  (KNOTS + 1)    // paired rows j=0..KNOTS
#define TSTRIDE ((size_t)TROWS * 512)
#define WCOLS 1408            // 128 q | 128 k | 384 v | 384 vecW | 384 oW
#define KB 16                 // knot-pairs per table-build block

typedef unsigned int  uint32;
typedef unsigned short ushort16;
typedef __attribute__((ext_vector_type(8))) short short8;
typedef __attribute__((ext_vector_type(4))) float f32x4;

__device__ __forceinline__ float siluf(float x){ return x / (1.0f + __expf(-x)); }
__device__ __forceinline__ float lerpf(float a, float b, float f){ return fmaf(f, b - a, a); }
__device__ __forceinline__ ushort16 f2b(float x){
    uint32 u = __float_as_uint(x);
    u += 0x7fffu + ((u >> 16) & 1u);
    return (ushort16)(u >> 16);
}
__device__ __forceinline__ float b2f(ushort16 u){ return __uint_as_float(((uint32)u) << 16); }
__device__ __forceinline__ uint32 packp(float a, float b){
    return (uint32)f2b(a) | ((uint32)f2b(b) << 16);
}
__device__ __forceinline__ float plo(uint32 u){ return __uint_as_float(u << 16); }
__device__ __forceinline__ float phi(uint32 u){ return __uint_as_float(u & 0xffff0000u); }
__device__ __forceinline__ float plerp(uint32 u, float f){ float a = plo(u); return fmaf(f, phi(u) - a, a); }

// ---------------- setup: counting sort of edges by dst ----------------
__global__ void k_zero(int* p, int n){
    int i = blockIdx.x*blockDim.x + threadIdx.x;
    if (i < n) p[i] = 0;
}

__global__ void k_count(const int* ei, int E, int* counts){
    int e = blockIdx.x*blockDim.x + threadIdx.x;
    if (e < E) atomicAdd(&counts[ei[E + e]], 1);
}

__global__ void k_scan(const int* counts, int* offsets, int* cursor, int n){
    __shared__ int part[1024];
    int tid = threadIdx.x;
    int PER = (n + 1023) >> 10;
    int base = tid * PER;
    int loc[8]; int s = 0;
    #pragma unroll 8
    for (int ii = 0; ii < 8; ii++){
        if (ii < PER){
            int idx = base + ii;
            int c = (idx < n) ? counts[idx] : 0;
            loc[ii] = s; s += c;
        }
    }
    part[tid] = s;
    __syncthreads();
    for (int off = 1; off < 1024; off <<= 1){
        int v = (tid >= off) ? part[tid - off] : 0;
        __syncthreads();
        part[tid] += v;
        __syncthreads();
    }
    int excl = (tid == 0) ? 0 : part[tid - 1];
    #pragma unroll 8
    for (int ii = 0; ii < 8; ii++){
        if (ii < PER){
            int idx = base + ii;
            if (idx < n){ int o = excl + loc[ii]; offsets[idx] = o; cursor[idx] = o; }
        }
    }
    if (tid == 1023) offsets[n] = part[1023];
}

__global__ void k_scatter(const int* ei, int E, int* cursor, int* eperm){
    int e = blockIdx.x*blockDim.x + threadIdx.x;
    if (e < E){
        int d = ei[E + e];
        int pos = atomicAdd(&cursor[d], 1);
        eperm[pos] = e;
    }
}

__global__ void k_edge_vals(const int* ei, const float* edge_vec, const int* eperm, int E,
                            int4* edata, float4* evn4){
    int row = blockIdx.x*blockDim.x + threadIdx.x;
    if (row >= E) return;
    int e = eperm[row];
    int s = ei[e], d = ei[E + e];
    float vx = edge_vec[e*3+0], vy = edge_vec[e*3+1], vz = edge_vec[e*3+2];
    float ew = sqrtf(vx*vx + vy*vy + vz*vz);
    float cut = (ew < CUTV) ? 0.5f*(__cosf(ew * 0.62831853071795864f) + 1.0f) : 0.0f;
    int ns = (s != d) ? 1 : 0;
    float inv = ns ? (1.0f/ew) : 1.0f;
    float un = fminf(ew * TSCALE, (float)KNOTS);
    int j = (int)un;
    float f = un - (float)j;
    int4 ed; ed.x = s; ed.y = j; ed.z = __float_as_int(f); ed.w = __float_as_int(cut);
    edata[row] = ed;
    float4 ev; ev.x = vx*inv; ev.y = vy*inv; ev.z = vz*inv; ev.w = ns ? 1.0f : 0.0f;
    evn4[row] = ev;
}

// zero pad rows of bf16 activation buffers (rows N..Nup / 3N..N3up)
__global__ void k_pad(ushort16* hb16, ushort16* vecm, ushort16* xab16, int N, int Nup, int N3up){
    int i = blockIdx.x*blockDim.x + threadIdx.x;
    int hpad = (Nup - N)*HID;
    int vpad = (N3up - 3*N)*HID;
    if (i < hpad){ hb16[(size_t)N*HID + i] = 0; xab16[(size_t)N*HID + i] = 0; }
    if (i < vpad) vecm[(size_t)3*N*HID + i] = 0;
}

// ---------------- tables: knot-blocked build ----------------
// Row layout (512 uint32 per knot-pair row j):
//   [0:128)   dk col c (paired bf16: f(j), f(j+1))
//   [128:512) dv packed per-thread: slot 128+3h+i = dv col ((h>>4)*48 + (h&15) + 16*i)
__global__ __launch_bounds__(512) void k_build_tables(
    const float* means, const float* betas,
    const float* dkW, const float* dkb, const float* dvW, const float* dvb,
    uint32* Tp){
    int jb = blockIdx.x * KB;
    int l  = blockIdx.y;
    int c  = threadIdx.x;
    __shared__ float ea_s[KB+1][NRBF+2];
    for (int idx = c; idx < (KB+1)*NRBF; idx += 512){
        int kk = idx / NRBF, r = idx - kk*NRBF;
        float d = (jb + kk) * TINV;
        float cut = (d < CUTV) ? 0.5f*(__cosf(d * 0.62831853071795864f) + 1.0f) : 0.0f;
        float u = __expf(-d) - means[r];
        ea_s[kk][r] = cut * __expf(-betas[r]*u*u);
    }
    __syncthreads();
    const float* Wcol; int stride; float bias;
    if (c < HID){
        Wcol = dkW + (size_t)l*NRBF*HID + c; stride = HID;
        bias = dkb[(size_t)l*HID + c];
    } else {
        int cc = c - HID;
        int h = cc / 3, i = cc - h*3;
        int col = ((h >> 4)*48 + (h & 15)) + 16*i;
        Wcol = dvW + (size_t)l*NRBF*384 + col; stride = 384;
        bias = dvb[(size_t)l*384 + col];
    }
    float a[KB+1];
    #pragma unroll
    for (int k = 0; k <= KB; k++) a[k] = bias;
    for (int r = 0; r < NRBF; r++){
        float w = Wcol[(size_t)r*stride];
        #pragma unroll
        for (int k = 0; k <= KB; k++) a[k] += ea_s[k][r]*w;
    }
    uint32* dst = Tp + (size_t)l*TSTRIDE + (size_t)jb*512 + c;
    float sp = siluf(a[0]);
    #pragma unroll
    for (int k = 0; k < KB; k++){
        int j = jb + k;
        if (j >= TROWS) break;
        float sn = siluf(a[k+1]);
        dst[(size_t)k*512] = packp(sp, sn);
        sp = sn;
    }
}

// NE table: paired f32
__global__ __launch_bounds__(128) void k_build_ne(
    const float* means, const float* betas,
    const float* dpW, const float* dpb, float2* Tne){
    int j = blockIdx.x, c = threadIdx.x;
    __shared__ float ea0[NRBF], ea1[NRBF];
    float d0 = j * TINV, d1 = (j+1) * TINV;
    float c0 = (d0 < CUTV) ? 0.5f*(__cosf(d0 * 0.62831853071795864f) + 1.0f) : 0.0f;
    float c1 = (d1 < CUTV) ? 0.5f*(__cosf(d1 * 0.62831853071795864f) + 1.0f) : 0.0f;
    if (c < NRBF){
        float m = means[c], be = betas[c];
        float u0 = __expf(-d0) - m, u1 = __expf(-d1) - m;
        ea0[c] = c0 * __expf(-be*u0*u0);
        ea1[c] = c1 * __expf(-be*u1*u1);
    }
    __syncthreads();
    float a0 = dpb[c], a1 = a0;
    #pragma unroll
    for (int r = 0; r < NRBF; r++){ float w = dpW[r*HID + c]; a0 += ea0[r]*w; a1 += ea1[r]*w; }
    float2 o; o.x = a0*c0; o.y = a1*c1;
    Tne[(size_t)j*HID + c] = o;
}

// ---------------- weight transpose: WT[l][col][k] bf16, cols: q|k|v|vecW|oW ----------------
__global__ __launch_bounds__(256) void k_build_wt(
    const float* qW, const float* kW, const float* vW, const float* vecW, const float* oW,
    ushort16* WT){
    int l = blockIdx.y; int c0 = blockIdx.x*32;
    const float* W; int C; int cs;
    if (c0 < 128)      { W = qW   + (size_t)l*HID*128; C = 128; cs = c0; }
    else if (c0 < 256) { W = kW   + (size_t)l*HID*128; C = 128; cs = c0-128; }
    else if (c0 < 640) { W = vW   + (size_t)l*HID*384; C = 384; cs = c0-256; }
    else if (c0 < 1024){ W = vecW + (size_t)l*HID*384; C = 384; cs = c0-640; }
    else               { W = oW   + (size_t)l*HID*384; C = 384; cs = c0-1024; }
    __shared__ ushort16 t[128][33];
    for (int i = threadIdx.x; i < 128*32; i += 256){
        int k = i >> 5, c = i & 31;
        t[k][c] = f2b(W[(size_t)k*C + cs + c]);
    }
    __syncthreads();
    ushort16* dst = WT + (size_t)l*WCOLS*HID + (size_t)c0*HID;
    for (int i = threadIdx.x; i < 128*32; i += 256){
        int c = i >> 7, k = i & 127;
        dst[(size_t)c*HID + k] = t[k][c];
    }
}

// ---------------- MFMA GEMMs ----------------
__global__ __launch_bounds__(256) void k_mfma01(
    const ushort16* __restrict__ hb16, const ushort16* __restrict__ vecm,
    const ushort16* __restrict__ WT,
    const float* __restrict__ qbias, const float* __restrict__ kbias, const float* __restrict__ vbias,
    float* __restrict__ qo, ushort16* __restrict__ ko, ushort16* __restrict__ vo,
    ushort16* __restrict__ vecout, int N){
    int cg = blockIdx.x;
    int rblk = blockIdx.y*64;
    const ushort16* A; int R; int cblk; const ushort16* wt;
    if (cg < 10){ A = hb16; R = N;   cblk = cg*64;      wt = WT; }
    else        { A = vecm; R = 3*N; cblk = (cg-10)*64; wt = WT + (size_t)640*HID; }
    if (rblk >= R) return;
    int wave = threadIdx.x >> 6, lane = threadIdx.x & 63;
    int r0 = rblk + wave*16;
    int l16 = lane & 15, lg = lane >> 4;
    short8 a[4];
    const ushort16* ar = A + (size_t)(r0 + l16)*HID + lg*8;
    #pragma unroll
    for (int ks = 0; ks < 4; ks++) a[ks] = *(const short8*)(ar + ks*32);
    f32x4 acc[4];
    #pragma unroll
    for (int ct = 0; ct < 4; ct++){ acc[ct][0]=0.f; acc[ct][1]=0.f; acc[ct][2]=0.f; acc[ct][3]=0.f; }
    #pragma unroll
    for (int ct = 0; ct < 4; ct++){
        const ushort16* br = wt + (size_t)(cblk + ct*16 + l16)*HID + lg*8;
        #pragma unroll
        for (int ks = 0; ks < 4; ks++){
            short8 b = *(const short8*)(br + ks*32);
            acc[ct] = __builtin_amdgcn_mfma_f32_16x16x32_bf16(a[ks], b, acc[ct], 0, 0, 0);
        }
    }
    #pragma unroll
    for (int ct = 0; ct < 4; ct++){
        int gc = cblk + ct*16 + l16;
        #pragma unroll
        for (int rg = 0; rg < 4; rg++){
            int row = r0 + lg*4 + rg;
            if (row >= R) continue;
            float v = acc[ct][rg];
            if (cg < 10){
                if (gc < 128)      qo[(size_t)row*HID + gc]       = v + qbias[gc];
                else if (gc < 256) ko[(size_t)row*HID + (gc-128)] = f2b(v + kbias[gc-128]);
                else               vo[(size_t)row*384 + (gc-256)] = f2b(v + vbias[gc-256]);
            } else {
                vecout[(size_t)row*384 + gc] = f2b(v);
            }
        }
    }
}

__global__ __launch_bounds__(256) void k_mfma_o(
    const ushort16* __restrict__ A, const ushort16* __restrict__ WT,
    const float* __restrict__ bias, float* __restrict__ out, int N){
    int cblk = blockIdx.x*64;
    int rblk = blockIdx.y*64;
    if (rblk >= N) return;
    int wave = threadIdx.x >> 6, lane = threadIdx.x & 63;
    int r0 = rblk + wave*16;
    int l16 = lane & 15, lg = lane >> 4;
    short8 a[4];
    const ushort16* ar = A + (size_t)(r0 + l16)*HID + lg*8;
    #pragma unroll
    for (int ks = 0; ks < 4; ks++) a[ks] = *(const short8*)(ar + ks*32);
    f32x4 acc[4];
    #pragma unroll
    for (int ct = 0; ct < 4; ct++){ acc[ct][0]=0.f; acc[ct][1]=0.f; acc[ct][2]=0.f; acc[ct][3]=0.f; }
    const ushort16* wt = WT + (size_t)1024*HID;
    #pragma unroll
    for (int ct = 0; ct < 4; ct++){
        const ushort16* br = wt + (size_t)(cblk + ct*16 + l16)*HID + lg*8;
        #pragma unroll
        for (int ks = 0; ks < 4; ks++){
            short8 b = *(const short8*)(br + ks*32);
            acc[ct] = __builtin_amdgcn_mfma_f32_16x16x32_bf16(a[ks], b, acc[ct], 0, 0, 0);
        }
    }
    #pragma unroll
    for (int ct = 0; ct < 4; ct++){
        int gc = cblk + ct*16 + l16;
        float bb = bias[gc];
        #pragma unroll
        for (int rg = 0; rg < 4; rg++){
            int row = r0 + lg*4 + rg;
            if (row >= N) continue;
            out[(size_t)row*384 + gc] = acc[ct][rg] + bb;
        }
    }
}

// ---------------- neighbor embedding ----------------
__global__ __launch_bounds__(128) void k_ne_agg(
    const int* offsets, const int4* edata, const float4* evn4, const float2* Tne,
    const int* z, const float* ne_emb, float* agg){
    int i = blockIdx.x, h = threadIdx.x;
    float acc = 0.f;
    int r0 = offsets[i], r1 = offsets[i+1];
    #pragma unroll 4
    for (int row = r0; row < r1; row++){
        int4 ed = edata[row];
        int s = ed.x, j = ed.y;
        float f = __int_as_float(ed.z);
        float mask = evn4[row].w;
        float2 tv = Tne[(size_t)j*HID + h];
        float w = lerpf(tv.x, tv.y, f) * mask;
        acc += w * ne_emb[(size_t)z[s]*HID + h];
    }
    agg[(size_t)i*HID + h] = acc;
}

// combine + LN(layer0) + zero vec state/mirror; hb16 output
__global__ __launch_bounds__(128) void k_combine_ln(
    const int* z, const float* emb, const float* agg, const float* cbW, const float* cbb,
    const float* lnw0, const float* lnb0,
    float* x, ushort16* hb16, float* vec, ushort16* vecm, int N){
    int n0 = blockIdx.x*8, h = threadIdx.x;
    __shared__ float in_s[8][2*HID];
    int nr = min(8, N - n0);
    for (int m = 0; m < nr; m++){
        in_s[m][h]       = emb[(size_t)z[n0+m]*HID + h];
        in_s[m][HID + h] = agg[(size_t)(n0+m)*HID + h];
    }
    __syncthreads();
    float acc[8];
    #pragma unroll
    for (int m = 0; m < 8; m++) acc[m] = 0.f;
    for (int kk = 0; kk < 2*HID; kk += 4){
        float w0 = cbW[(kk+0)*HID + h], w1 = cbW[(kk+1)*HID + h];
        float w2 = cbW[(kk+2)*HID + h], w3 = cbW[(kk+3)*HID + h];
        #pragma unroll
        for (int m = 0; m < 8; m++){
            const float* a = &in_s[m][kk];
            acc[m] += a[0]*w0 + a[1]*w1 + a[2]*w2 + a[3]*w3;
        }
    }
    float bias = cbb[h], w = lnw0[h], bb = lnb0[h];
    __shared__ float r1_[2], r2_[2];
    int wid = h >> 6;
    for (int m = 0; m < nr; m++){
        int n = n0 + m;
        float v = acc[m] + bias;
        x[(size_t)n*HID + h] = v;
        float s1 = v, s2 = v*v;
        #pragma unroll
        for (int o = 32; o; o >>= 1){ s1 += __shfl_xor(s1, o, 64); s2 += __shfl_xor(s2, o, 64); }
        if ((h & 63) == 0){ r1_[wid] = s1; r2_[wid] = s2; }
        __syncthreads();
        float sum = r1_[0] + r1_[1], sumsq = r2_[0] + r2_[1];
        float mean = sum * (1.f/HID);
        float var = sumsq * (1.f/HID) - mean*mean;
        float inv = rsqrtf(var + 1e-5f);
        hb16[(size_t)n*HID + h] = f2b((v - mean)*inv*w + bb);
        __syncthreads();
        vec [(size_t)n*384 + h]       = 0.f;
        vec [(size_t)n*384 + 128 + h] = 0.f;
        vec [(size_t)n*384 + 256 + h] = 0.f;
        vecm[(size_t)n*384 + h]       = 0;
        vecm[(size_t)n*384 + 128 + h] = 0;
        vecm[(size_t)n*384 + 256 + h] = 0;
    }
}

// ---------------- fused edge aggregation (bf16 gathers, 4-edge pipeline) ----------------
__global__ __launch_bounds__(128) void k_edge_agg(
    const int* __restrict__ offsets, const int4* __restrict__ edata,
    const float4* __restrict__ evn4, const uint32* __restrict__ Tp,
    const float* __restrict__ q, const ushort16* __restrict__ kb16,
    const ushort16* __restrict__ vb16, const ushort16* __restrict__ vecm,
    ushort16* __restrict__ xa16, float* __restrict__ va){
    int i = blockIdx.x, h = threadIdx.x;
    int head = h >> 4;
    int c0 = head*48 + (h & 15);
    float qv = q[(size_t)i*HID + h];
    float axa = 0.f, av0 = 0.f, av1 = 0.f, av2 = 0.f;
    int r0 = offsets[i], r1 = offsets[i+1];
    for (int t0 = r0; t0 < r1; t0 += 4){
        float f_[4], cut_[4], ex_[4], ey_[4], ez_[4];
        uint32 tdk_[4], tdv0_[4], tdv1_[4], tdv2_[4];
        ushort16 kv_[4], v0_[4], v1_[4], v2_[4], vc0_[4], vc1_[4], vc2_[4];
        #pragma unroll
        for (int u = 0; u < 4; u++){
            int row = min(t0 + u, r1 - 1);
            int4 ed = edata[row];
            int s = ed.x, j = ed.y;
            f_[u]   = __int_as_float(ed.z);
            cut_[u] = __int_as_float(ed.w);
            const uint32* tp = Tp + (size_t)j*512;
            tdk_[u]  = tp[h];
            const uint32* q3 = tp + 128 + 3*h;
            tdv0_[u] = q3[0];
            tdv1_[u] = q3[1];
            tdv2_[u] = q3[2];
            kv_[u] = kb16[(size_t)s*HID + h];
            const ushort16* vr = vb16 + (size_t)s*384;
            v0_[u] = vr[c0]; v1_[u] = vr[c0+16]; v2_[u] = vr[c0+32];
            const ushort16* vc = vecm + (size_t)s*384;
            vc0_[u] = vc[h]; vc1_[u] = vc[128+h]; vc2_[u] = vc[256+h];
            float4 ev = evn4[row];
            ex_[u] = ev.x; ey_[u] = ev.y; ez_[u] = ev.z;
        }
        #pragma unroll
        for (int u = 0; u < 4; u++){
            if (t0 + u >= r1) break;
            float f = f_[u];
            float dk = plerp(tdk_[u], f);
            float p = qv * b2f(kv_[u]) * dk;
            p += __shfl_xor(p, 1, 64);
            p += __shfl_xor(p, 2, 64);
            p += __shfl_xor(p, 4, 64);
            p += __shfl_xor(p, 8, 64);
            float attn = siluf(p) * cut_[u];
            float dv0 = plerp(tdv0_[u], f);
            float dv1 = plerp(tdv1_[u], f);
            float dv2 = plerp(tdv2_[u], f);
            axa += b2f(v0_[u]) * dv0 * attn;
            float w1v = b2f(v1_[u]) * dv1;
            float w2v = b2f(v2_[u]) * dv2;
            av0 += b2f(vc0_[u])*w1v + w2v*ex_[u];
            av1 += b2f(vc1_[u])*w1v + w2v*ey_[u];
            av2 += b2f(vc2_[u])*w1v + w2v*ez_[u];
        }
    }
    xa16[(size_t)i*HID + h] = f2b(axa);
    va[(size_t)i*384 + h]       = av0;
    va[(size_t)i*384 + 128 + h] = av1;
    va[(size_t)i*384 + 256 + h] = av2;
}

// ---------------- fused vecdot + residual update + next-layer LN ----------------
__global__ __launch_bounds__(128) void k_update_ln(
    float* __restrict__ x, float* __restrict__ vec, ushort16* __restrict__ vecm,
    const float* __restrict__ o, const ushort16* __restrict__ vecout, const float* __restrict__ va,
    const float* __restrict__ lnw_n, const float* __restrict__ lnb_n,
    ushort16* __restrict__ hb16, float* __restrict__ outx, float* __restrict__ outv, int fin){
    int n = blockIdx.x, h = threadIdx.x;
    const ushort16* vo = vecout + (size_t)n*1152;
    float vdot = b2f(vo[h])*b2f(vo[128+h]) + b2f(vo[384+h])*b2f(vo[512+h])
               + b2f(vo[768+h])*b2f(vo[896+h]);
    const float* on = o + (size_t)n*384;
    float xv = x[(size_t)n*HID + h] + vdot*on[128 + h] + on[256 + h];
    float o1 = on[h];
    size_t vb = (size_t)n*384;
    float v0 = vec[vb + h]       + b2f(vo[256  + h])*o1 + va[vb + h];
    float v1 = vec[vb + 128 + h] + b2f(vo[640  + h])*o1 + va[vb + 128 + h];
    float v2 = vec[vb + 256 + h] + b2f(vo[1024 + h])*o1 + va[vb + 256 + h];
    float s1 = xv, s2 = xv*xv;
    #pragma unroll
    for (int oo = 32; oo; oo >>= 1){ s1 += __shfl_xor(s1, oo, 64); s2 += __shfl_xor(s2, oo, 64); }
    __shared__ float r1_[2], r2_[2];
    int wid = h >> 6;
    if ((h & 63) == 0){ r1_[wid] = s1; r2_[wid] = s2; }
    __syncthreads();
    float sum = r1_[0] + r1_[1], sumsq = r2_[0] + r2_[1];
    float mean = sum * (1.f/HID);
    float var = sumsq * (1.f/HID) - mean*mean;
    float inv = rsqrtf(var + 1e-5f);
    float lnv = (xv - mean)*inv*lnw_n[h] + lnb_n[h];
    if (!fin){
        x[(size_t)n*HID + h] = xv;
        vec[vb + h] = v0; vec[vb + 128 + h] = v1; vec[vb + 256 + h] = v2;
        vecm[vb + h] = f2b(v0); vecm[vb + 128 + h] = f2b(v1); vecm[vb + 256 + h] = f2b(v2);
        hb16[(size_t)n*HID + h] = f2b(lnv);
    } else {
        outx[(size_t)n*HID + h] = lnv;
        outv[vb + h] = v0; outv[vb + 128 + h] = v1; outv[vb + 256 + h] = v2;
    }
}

// ---------------- host ----------------
extern "C" void kernel_launch(void* const* d_in, const int* in_sizes, int n_in,
                              void* d_out, int out_size, void* d_ws, size_t ws_size,
                              hipStream_t stream){
    const int*   z        = (const int*)  d_in[0];
    const int*   ei       = (const int*)  d_in[1];
    const float* edge_vec = (const float*)d_in[2];
    const float* emb      = (const float*)d_in[3];
    const float* means    = (const float*)d_in[4];
    const float* betas    = (const float*)d_in[5];
    const float* ne_emb   = (const float*)d_in[6];
    const float* dpW      = (const float*)d_in[7];
    const float* dpb      = (const float*)d_in[8];
    const float* cbW      = (const float*)d_in[9];
    const float* cbb      = (const float*)d_in[10];
    const float* lnw      = (const float*)d_in[11];
    const float* lnb      = (const float*)d_in[12];
    const float* qW       = (const float*)d_in[13];
    const float* qb       = (const float*)d_in[14];
    const float* kW       = (const float*)d_in[15];
    const float* kb       = (const float*)d_in[16];
    const float* vW       = (const float*)d_in[17];
    const float* vb       = (const float*)d_in[18];
    const float* oW       = (const float*)d_in[19];
    const float* obias    = (const float*)d_in[20];
    const float* vecW     = (const float*)d_in[21];
    const float* dkW      = (const float*)d_in[22];
    const float* dkb      = (const float*)d_in[23];
    const float* dvW      = (const float*)d_in[24];
    const float* dvb      = (const float*)d_in[25];
    const float* onw      = (const float*)d_in[26];
    const float* onb      = (const float*)d_in[27];

    int N = in_sizes[0];
    int E = in_sizes[1] / 2;
    int Nup  = ((N + 63) >> 6) << 6;
    int N3up = ((3*N + 63) >> 6) << 6;

    char* p = (char*)d_ws;
    auto alloc = [&](size_t bytes){ void* r = (void*)p; p += (bytes + 255) & ~(size_t)255; return r; };
    int*      counts  = (int*)     alloc((size_t)N*4);
    int*      offsets = (int*)     alloc((size_t)(N+1)*4);
    int*      cursor  = (int*)     alloc((size_t)N*4);
    int*      eperm   = (int*)     alloc((size_t)E*4);
    int4*     edata   = (int4*)    alloc((size_t)E*16);
    float4*   evn4    = (float4*)  alloc((size_t)E*16);
    uint32*   Tp      = (uint32*)  alloc((size_t)NLAYERS*TSTRIDE*4);
    float2*   Tne     = (float2*)  alloc((size_t)TROWS*HID*8);
    ushort16* WT      = (ushort16*)alloc((size_t)NLAYERS*WCOLS*HID*2);
    float*    agg     = (float*)   alloc((size_t)N*HID*4);
    float*    xb      = (float*)   alloc((size_t)N*HID*4);
    ushort16* hb16    = (ushort16*)alloc((size_t)Nup*HID*2);
    float*    qb_     = (float*)   alloc((size_t)N*HID*4);
    ushort16* kb16    = (ushort16*)alloc((size_t)N*HID*2);
    ushort16* vb16    = (ushort16*)alloc((size_t)N*384*2);
    ushort16* vecm    = (ushort16*)alloc((size_t)N3up*HID*2);
    float*    vecb    = (float*)   alloc((size_t)N*384*4);
    ushort16* vecout  = (ushort16*)alloc((size_t)N*1152*2);
    ushort16* xab16   = (ushort16*)alloc((size_t)Nup*HID*2);
    float*    vab     = (float*)   alloc((size_t)N*384*4);
    float*    ob_     = (float*)   alloc((size_t)N*384*4);

    k_zero<<<(N+255)/256, 256, 0, stream>>>(counts, N);
    k_count<<<(E+255)/256, 256, 0, stream>>>(ei, E, counts);
    k_scan<<<1, 1024, 0, stream>>>(counts, offsets, cursor, N);
    k_scatter<<<(E+255)/256, 256, 0, stream>>>(ei, E, cursor, eperm);
    k_edge_vals<<<(E+255)/256, 256, 0, stream>>>(ei, edge_vec, eperm, E, edata, evn4);
    k_pad<<<((Nup-N)*HID + (N3up-3*N)*HID + 255)/256 + 1, 256, 0, stream>>>(hb16, vecm, xab16, N, Nup, N3up);

    k_build_tables<<<dim3((TROWS + KB - 1)/KB, NLAYERS), 512, 0, stream>>>(means, betas, dkW, dkb, dvW, dvb, Tp);
    k_build_ne<<<TROWS, 128, 0, stream>>>(means, betas, dpW, dpb, Tne);
    k_build_wt<<<dim3(WCOLS/32, NLAYERS), 256, 0, stream>>>(qW, kW, vW, vecW, oW, WT);
    k_ne_agg<<<N, 128, 0, stream>>>(offsets, edata, evn4, Tne, z, ne_emb, agg);
    k_combine_ln<<<(N+7)/8, 128, 0, stream>>>(z, emb, agg, cbW, cbb, lnw, lnb,
                                              xb, hb16, vecb, vecm, N);

    float* outx = (float*)d_out;
    float* outv = (float*)d_out + (size_t)N*HID;

    for (int l = 0; l < NLAYERS; l++){
        const ushort16* WTl = WT + (size_t)l*WCOLS*HID;
        k_mfma01<<<dim3(16, (3*N+63)/64), 256, 0, stream>>>(hb16, vecm, WTl,
            qb + (size_t)l*HID, kb + (size_t)l*HID, vb + (size_t)l*384,
            qb_, kb16, vb16, vecout, N);
        k_edge_agg<<<N, 128, 0, stream>>>(offsets, edata, evn4, Tp + (size_t)l*TSTRIDE,
                                          qb_, kb16, vb16, vecm, xab16, vab);
        k_mfma_o<<<dim3(6, (N+63)/64), 256, 0, stream>>>(xab16, WTl, obias + (size_t)l*384, ob_, N);
        int fin = (l == NLAYERS-1);
        k_update_ln<<<N, 128, 0, stream>>>(xb, vecb, vecm, ob_, vecout, vab,
            fin ? onw : lnw + (size_t)(l+1)*HID,
            fin ? onb : lnb + (size_t)(l+1)*HID,
            hb16, outx, outv, fin);
    }
}